// Round 14
// baseline (2049.403 us; speedup 1.0000x reference)
//
#include <hip/hip_runtime.h>
#include <math.h>

typedef unsigned short u16;
typedef _Float16 f16;
typedef __attribute__((ext_vector_type(8))) _Float16 f16x8;
typedef __attribute__((ext_vector_type(4))) float f32x4;

// ---- problem constants ----
constexpr int cB   = 2;
constexpr int cS   = 1024;
constexpr int cD   = 2048;
constexpr int cH   = 8;
constexpr int cHD  = 256;
constexpr int cKV  = 4;
constexpr int cGHD = 512;
constexpr int cGKV = 4;
constexpr int cROT = 128;
constexpr int cF   = 8192;
constexpr int cV   = 32000;
constexpr int cWIN = 512;
constexpr int cM   = cB * cS;   // 2048 token rows
constexpr float cEPS = 1e-6f;
constexpr size_t MB = 1024 * 1024;

__device__ inline u16 f2h(float x) { union { f16 h; u16 u; } c; c.h = (f16)x; return c.u; }
__device__ inline float h2f(u16 v) { union { u16 u; f16 h; } c; c.u = v; return (float)c.h; }

// swizzled LDS u16-index: [128][32] u16 rows, 16B chunks XOR'd by (row>>1)&3.
__device__ inline int swz16(int row, int chunk) {
    return row * 32 + ((chunk ^ ((row >> 1) & 3)) << 3);
}
// swizzle for BK=64 fp16 arrays (qk/pv): [row][64] u16, 16B chunk ^= row&7
__device__ inline int swzK(int row, int ch) {
    return row * 64 + ((ch ^ (row & 7)) << 3);
}

// async 16B global->LDS (wave-uniform LDS base + lane*16; per-lane global addr)
typedef __attribute__((address_space(1))) const unsigned int gu32;
typedef __attribute__((address_space(3))) unsigned int lu32;
__device__ inline void ldsload16(const u16* g, u16* l) {
    __builtin_amdgcn_global_load_lds((gu32*)g, (lu32*)l, 16, 0, 0);
}

__device__ inline float gelu_tanh(float v) {
    const float t = tanhf(0.7978845608028654f * (v + 0.044715f * v * v * v));
    return 0.5f * v * (1.f + t);
}

// ---------------------------------------------------------------------------
// embed lookup * sqrt(D)
// ---------------------------------------------------------------------------
__global__ void embed_kernel(const int* __restrict__ tok,
                             const float* __restrict__ emb,
                             float* __restrict__ out) {
    const int row = blockIdx.x;
    const int t = tok[row];
    const float* e = emb + (size_t)t * cD;
    float* o = out + (size_t)row * cD;
    const float sc = sqrtf((float)cD);
    for (int d = threadIdx.x; d < cD; d += blockDim.x) o[d] = e[d] * sc;
}

// ---------------------------------------------------------------------------
// row RMS norm fp32->fp32.  Input rows may live in a wider matrix:
// in offset = (row/nh)*xld + (row%nh)*dim ; output is dense (row*dim).
// ---------------------------------------------------------------------------
__global__ void rms_kernel(const float* __restrict__ x,
                           const float* __restrict__ w,
                           float* __restrict__ out, int dim, int xld, int nh) {
    const int row = blockIdx.x;
    const float* xr = x + (size_t)(row / nh) * xld + (size_t)(row % nh) * dim;
    float* orow = out + (size_t)row * dim;
    float ss = 0.f;
    for (int d = threadIdx.x; d < dim; d += blockDim.x) { float v = xr[d]; ss += v * v; }
    for (int o = 32; o >= 1; o >>= 1) ss += __shfl_xor(ss, o);
    __shared__ float rb[8];
    if ((threadIdx.x & 63) == 0) rb[threadIdx.x >> 6] = ss;
    __syncthreads();
    ss = rb[0] + rb[1] + rb[2] + rb[3];
    const float r = rsqrtf(ss / dim + cEPS);
    for (int d = threadIdx.x; d < dim; d += blockDim.x)
        orow[d] = xr[d] * r * (w ? w[d] : 1.f);
}

// row RMS norm fp32 -> fp16 (dense both sides)
__global__ void rms_f16_kernel(const float* __restrict__ x,
                               const float* __restrict__ w,
                               u16* __restrict__ out, int dim) {
    const int row = blockIdx.x;
    const float* xr = x + (size_t)row * dim;
    u16* orow = out + (size_t)row * dim;
    float ss = 0.f;
    for (int d = threadIdx.x; d < dim; d += blockDim.x) { float v = xr[d]; ss += v * v; }
    for (int o = 32; o >= 1; o >>= 1) ss += __shfl_xor(ss, o);
    __shared__ float rb[8];
    if ((threadIdx.x & 63) == 0) rb[threadIdx.x >> 6] = ss;
    __syncthreads();
    ss = rb[0] + rb[1] + rb[2] + rb[3];
    const float r = rsqrtf(ss / dim + cEPS);
    for (int d = threadIdx.x; d < dim; d += blockDim.x)
        orow[d] = f2h(xr[d] * r * (w ? w[d] : 1.f));
}

// ---------------------------------------------------------------------------
// fused: x_new = (res + y*rms(y)*w_add) * scal ; ab = fp16(x_new*rms(x_new)*w_norm)
// ---------------------------------------------------------------------------
__global__ __launch_bounds__(256) void addnorm_kernel(const float* __restrict__ res,
                                                      const float* __restrict__ y,
                                                      const float* __restrict__ w_add,
                                                      const float* __restrict__ scal,
                                                      const float* __restrict__ w_norm,
                                                      float* __restrict__ xout,
                                                      u16* __restrict__ abo) {
    const int row = blockIdx.x;
    const float* yr = y + (size_t)row * cD;
    const float* rr = res + (size_t)row * cD;
    float* xo = xout + (size_t)row * cD;
    u16* ao = abo + (size_t)row * cD;
    const int tid = threadIdx.x;
    __shared__ float rb[4];

    float yl[8], xl[8];
    float ss = 0.f;
#pragma unroll
    for (int j = 0; j < 8; ++j) { yl[j] = yr[tid + j * 256]; ss += yl[j] * yl[j]; }
    for (int o = 32; o >= 1; o >>= 1) ss += __shfl_xor(ss, o);
    if ((tid & 63) == 0) rb[tid >> 6] = ss;
    __syncthreads();
    ss = rb[0] + rb[1] + rb[2] + rb[3];
    const float r1 = rsqrtf(ss / cD + cEPS);
    const float sc = scal ? *scal : 1.f;

    float ss2 = 0.f;
#pragma unroll
    for (int j = 0; j < 8; ++j) {
        const int d = tid + j * 256;
        xl[j] = (rr[d] + yl[j] * r1 * w_add[d]) * sc;
        ss2 += xl[j] * xl[j];
    }
    for (int o = 32; o >= 1; o >>= 1) ss2 += __shfl_xor(ss2, o);
    __syncthreads();
    if ((tid & 63) == 0) rb[tid >> 6] = ss2;
    __syncthreads();
    ss2 = rb[0] + rb[1] + rb[2] + rb[3];
    const float r2 = rsqrtf(ss2 / cD + cEPS);
#pragma unroll
    for (int j = 0; j < 8; ++j) {
        const int d = tid + j * 256;
        xo[d] = xl[j];
        ao[d] = f2h(xl[j] * r2 * w_norm[d]);
    }
}

// ---------------------------------------------------------------------------
// fused: rms(x)*w -> partial rope -> fp16.  one block (128 thr) per head-row.
// input offset = (row/NH)*xld + (row%NH)*HDIM ; out dense row*HDIM.
// ---------------------------------------------------------------------------
__global__ __launch_bounds__(128) void rmsrope_kernel(const float* __restrict__ x,
                                                      const float* __restrict__ w,
                                                      u16* __restrict__ out,
                                                      int NH, int HDIM, int rot,
                                                      float theta, int xld) {
    const int row = blockIdx.x;
    const int s = (row / NH) % cS;
    const float* xr = x + (size_t)(row / NH) * xld + (size_t)(row % NH) * HDIM;
    u16* orow = out + (size_t)row * HDIM;
    const int tid = threadIdx.x;
    const int np = HDIM >> 1;
    __shared__ float rb[2];

    float v1[2], v2[2];
    float ss = 0.f;
    for (int p = tid, j = 0; p < np; p += 128, ++j) {
        v1[j] = xr[2 * p]; v2[j] = xr[2 * p + 1];
        ss += v1[j] * v1[j] + v2[j] * v2[j];
    }
    for (int o = 32; o >= 1; o >>= 1) ss += __shfl_xor(ss, o);
    if ((tid & 63) == 0) rb[tid >> 6] = ss;
    __syncthreads();
    ss = rb[0] + rb[1];
    const float r = rsqrtf(ss / HDIM + cEPS);
    const int halfrot = rot >> 1;
    for (int p = tid, j = 0; p < np; p += 128, ++j) {
        const float a = v1[j] * r * w[2 * p];
        const float b = v2[j] * r * w[2 * p + 1];
        float o1 = a, o2 = b;
        if (p < halfrot) {
            const float inv = powf(theta, -(2.f * p) / (float)rot);
            const float ang = (float)s * inv;
            const float c = cosf(ang), sn = sinf(ang);
            o1 = a * c - b * sn;
            o2 = a * sn + b * c;
        }
        orow[2 * p]     = f2h(o1);
        orow[2 * p + 1] = f2h(o2);
    }
}

// ---------------------------------------------------------------------------
// fp32 [K][N] (row stride ldin) -> fp16 [N][K]
// ---------------------------------------------------------------------------
__global__ __launch_bounds__(256) void tcast_kernel(const float* __restrict__ in,
                                                    u16* __restrict__ out,
                                                    int K, int N, int ldin) {
    __shared__ float t[32][33];
    const int kt = blockIdx.y * 32, nt = blockIdx.x * 32;
    const int tx = threadIdx.x & 31, ty = threadIdx.x >> 5;   // ty 0..7
#pragma unroll
    for (int j = 0; j < 4; ++j)
        t[ty + j * 8][tx] = in[(size_t)(kt + ty + j * 8) * ldin + nt + tx];
    __syncthreads();
#pragma unroll
    for (int j = 0; j < 4; ++j)
        out[(size_t)(nt + ty + j * 8) * K + kt + tx] = f2h(t[tx][ty + j * 8]);
}

// V fp32 [B,S,KVH,HDIM] dense -> Vt fp16 [B*KVH, HDIM, S]
__global__ __launch_bounds__(256) void vtrans_kernel(const float* __restrict__ V,
                                                     u16* __restrict__ Vt,
                                                     int HDIM, int KVH) {
    __shared__ float t[32][33];
    const int bk = blockIdx.z;
    const int b = bk / KVH, kh = bk % KVH;
    const int st = blockIdx.y * 32, dt = blockIdx.x * 32;
    const int tx = threadIdx.x & 31, ty = threadIdx.x >> 5;
#pragma unroll
    for (int j = 0; j < 4; ++j)
        t[ty + j * 8][tx] = V[((size_t)(b * cS + st + ty + j * 8) * KVH + kh) * HDIM + dt + tx];
    __syncthreads();
#pragma unroll
    for (int j = 0; j < 4; ++j)
        Vt[((size_t)bk * HDIM + dt + ty + j * 8) * cS + st + tx] = f2h(t[tx][ty + j * 8]);
}

// ---------------------------------------------------------------------------
// fp16 MFMA GEMM (m97 structure, 128x128, BK=32): for small-N GEMMs.
// ---------------------------------------------------------------------------
template<bool F16_OUT, bool GELU>
__global__ __launch_bounds__(256) void gemm_f16(const u16* __restrict__ A,
                                                const u16* __restrict__ Bt,
                                                void* __restrict__ Cout,
                                                const u16* __restrict__ gate,
                                                int Mt, int K, int ldc) {
    __shared__ u16 As[128 * 32];
    __shared__ u16 Bs[128 * 32];
    const int nwg = gridDim.x;
    const int q8 = nwg >> 3;
    const int dd = blockIdx.x;
    const int wk = (dd & 7) * q8 + (dd >> 3);       // bijective XCD-contiguous
    const int bm = (wk % Mt) * 128;
    const int bn = (wk / Mt) * 128;
    const int tid = threadIdx.x;
    const int lane = tid & 63;
    const int wv = tid >> 6;
    const int wr = (wv >> 1) * 64, wc = (wv & 1) * 64;
    const int r15 = lane & 15, hi16 = lane >> 4;

    f32x4 acc[4][4];
#pragma unroll
    for (int m = 0; m < 4; ++m)
#pragma unroll
        for (int n = 0; n < 4; ++n) acc[m][n] = (f32x4){0.f, 0.f, 0.f, 0.f};

    int rowS[2], koS[2];
#pragma unroll
    for (int i = 0; i < 2; ++i) {
        const int s = i * 256 + tid;
        rowS[i] = s >> 2;
        koS[i] = ((s & 3) ^ ((rowS[i] >> 1) & 3)) * 8;
    }
    u16* ldsA0 = &As[(wv * 64) * 8];
    u16* ldsA1 = &As[(256 + wv * 64) * 8];
    u16* ldsB0 = &Bs[(wv * 64) * 8];
    u16* ldsB1 = &Bs[(256 + wv * 64) * 8];

    for (int k0 = 0; k0 < K; k0 += 32) {
        __syncthreads();
        ldsload16(&A [(size_t)(bm + rowS[0]) * K + k0 + koS[0]], ldsA0);
        ldsload16(&A [(size_t)(bm + rowS[1]) * K + k0 + koS[1]], ldsA1);
        ldsload16(&Bt[(size_t)(bn + rowS[0]) * K + k0 + koS[0]], ldsB0);
        ldsload16(&Bt[(size_t)(bn + rowS[1]) * K + k0 + koS[1]], ldsB1);
        __syncthreads();
        f16x8 af[4], bf4[4];
#pragma unroll
        for (int m = 0; m < 4; ++m)
            af[m] = *(const f16x8*)&As[swz16(wr + m * 16 + r15, hi16)];
#pragma unroll
        for (int n = 0; n < 4; ++n)
            bf4[n] = *(const f16x8*)&Bs[swz16(wc + n * 16 + r15, hi16)];
#pragma unroll
        for (int m = 0; m < 4; ++m)
#pragma unroll
            for (int n = 0; n < 4; ++n)
                acc[m][n] = __builtin_amdgcn_mfma_f32_16x16x32_f16(af[m], bf4[n], acc[m][n], 0, 0, 0);
    }
#pragma unroll
    for (int m = 0; m < 4; ++m)
#pragma unroll
        for (int n = 0; n < 4; ++n)
#pragma unroll
            for (int r = 0; r < 4; ++r) {
                const int row = bm + wr + m * 16 + hi16 * 4 + r;
                const int col = bn + wc + n * 16 + r15;
                const size_t idx = (size_t)row * ldc + col;
                float v = acc[m][n][r];
                if (GELU) v = gelu_tanh(h2f(gate[idx])) * v;
                if (F16_OUT) ((u16*)Cout)[idx] = f2h(v);
                else         ((float*)Cout)[idx] = v;
            }
}

// ---------------------------------------------------------------------------
// 256x256-tile fp16 GEMM (round-10 proven variant): BK=32, 512 threads
// (8 waves 2Mx4N), double-buffered 64KB LDS, prefetch next K-tile via
// global_load_lds BEFORE computing current, single __syncthreads per K-step,
// setprio around MFMA cluster. LDS row-pairs of 128B, chunk8 ^= rp&7 swizzle;
// staging pre-swizzles the global source so linear gload_lds dest matches.
// ---------------------------------------------------------------------------
template<bool F16_OUT, bool GELU>
__global__ __launch_bounds__(512) void gemm256(const u16* __restrict__ A,
                                               const u16* __restrict__ Bt,
                                               void* __restrict__ Cout,
                                               const u16* __restrict__ gate,
                                               int Mt, int K, int ldc) {
    __shared__ u16 As[2][256 * 32];
    __shared__ u16 Bs[2][256 * 32];
    const int nwg = gridDim.x;
    const int q8 = nwg >> 3;
    const int dd = blockIdx.x;
    const int wk = (dd & 7) * q8 + (dd >> 3);   // bijective XCD-contiguous
    const int bm = (wk % Mt) * 256;
    const int bn = (wk / Mt) * 256;
    const int tid = threadIdx.x;
    const int lane = tid & 63;
    const int wid = tid >> 6;
    const int wm = wid >> 2, wn = wid & 3;      // wave grid 2x4
    const int r15 = lane & 15, hi16 = lane >> 4;

    f32x4 acc[8][4];
#pragma unroll
    for (int mi = 0; mi < 8; ++mi)
#pragma unroll
        for (int ni = 0; ni < 4; ++ni) acc[mi][ni] = (f32x4){0.f, 0.f, 0.f, 0.f};

    // staging pre-swizzle: lane slot (rp_local = lane>>3, slot = lane&7) holds
    // data chunk8 = slot ^ rp_local -> source row/kchunk derived from it.
    const int rpl  = lane >> 3;
    const int ch8d = (lane & 7) ^ rpl;
    const int sr   = wid * 16 + rpl * 2 + (ch8d >> 2);   // + i*128 (+ bm/bn)
    const int sk   = (ch8d & 3) * 8;                     // k offset within 32
    const int ldst = wid * 512;                          // u16; + i*4096

    const int nt = K / 32;
    {   // prologue: stage tile 0 into buf 0
        ldsload16(&A [(size_t)(bm + sr)       * K + sk], &As[0][ldst]);
        ldsload16(&A [(size_t)(bm + 128 + sr) * K + sk], &As[0][4096 + ldst]);
        ldsload16(&Bt[(size_t)(bn + sr)       * K + sk], &Bs[0][ldst]);
        ldsload16(&Bt[(size_t)(bn + 128 + sr) * K + sk], &Bs[0][4096 + ldst]);
    }
    __syncthreads();

    for (int t = 0; t < nt; ++t) {
        const int cur = t & 1;
        if (t + 1 < nt) {   // prefetch next tile into other buffer (overlaps compute)
            const int nb = cur ^ 1;
            const size_t k0 = (size_t)(t + 1) * 32 + sk;
            ldsload16(&A [(size_t)(bm + sr)       * K + k0], &As[nb][ldst]);
            ldsload16(&A [(size_t)(bm + 128 + sr) * K + k0], &As[nb][4096 + ldst]);
            ldsload16(&Bt[(size_t)(bn + sr)       * K + k0], &Bs[nb][ldst]);
            ldsload16(&Bt[(size_t)(bn + 128 + sr) * K + k0], &Bs[nb][4096 + ldst]);
        }
        const u16* Ab = As[cur];
        const u16* Bb = Bs[cur];
        f16x8 bf[4], af[8];
#pragma unroll
        for (int ni = 0; ni < 4; ++ni) {
            const int row = wn * 64 + ni * 16 + r15;
            const int rp = row >> 1;
            const int slot = (((row & 1) << 2) | hi16) ^ (rp & 7);
            bf[ni] = *(const f16x8*)&Bb[rp * 64 + slot * 8];
        }
#pragma unroll
        for (int mi = 0; mi < 8; ++mi) {
            const int row = wm * 128 + mi * 16 + r15;
            const int rp = row >> 1;
            const int slot = (((row & 1) << 2) | hi16) ^ (rp & 7);
            af[mi] = *(const f16x8*)&Ab[rp * 64 + slot * 8];
        }
        __builtin_amdgcn_s_setprio(1);
#pragma unroll
        for (int mi = 0; mi < 8; ++mi)
#pragma unroll
            for (int ni = 0; ni < 4; ++ni)
                acc[mi][ni] = __builtin_amdgcn_mfma_f32_16x16x32_f16(af[mi], bf[ni], acc[mi][ni], 0, 0, 0);
        __builtin_amdgcn_s_setprio(0);
        __syncthreads();   // drains vmcnt (prefetch landed) + all reads consumed
    }

#pragma unroll
    for (int mi = 0; mi < 8; ++mi)
#pragma unroll
        for (int ni = 0; ni < 4; ++ni)
#pragma unroll
            for (int r = 0; r < 4; ++r) {
                const int row = bm + wm * 128 + mi * 16 + hi16 * 4 + r;
                const int col = bn + wn * 64 + ni * 16 + r15;
                const size_t idx = (size_t)row * ldc + col;
                float v = acc[mi][ni][r];
                if (GELU) v = gelu_tanh(h2f(gate[idx])) * v;
                if (F16_OUT) ((u16*)Cout)[idx] = f2h(v);
                else         ((float*)Cout)[idx] = v;
            }
}

// ---------------------------------------------------------------------------
// logits 256x256 GEMM, B read DIRECTLY from fp32 (embed [N][K]) and converted
// during reg-staged LDS write. A via global_load_lds (as gemm256). Same
// double-buffer: issue A gload + B float4 loads for tile t+1 at loop top,
// MFMA tile t, then pack+ds_write B(t+1) after the MFMA (loads arrived),
// single __syncthreads per K-step. LDS layout identical to gemm256.
// ---------------------------------------------------------------------------
__global__ __launch_bounds__(512) void gemm_logits256(const u16* __restrict__ A,
                                                      const float* __restrict__ Bf,
                                                      float* __restrict__ Cout,
                                                      int Mt, int K, int ldc) {
    __shared__ u16 As[2][256 * 32];
    __shared__ u16 Bs[2][256 * 32];
    const int nwg = gridDim.x;
    const int q8 = nwg >> 3;
    const int dd = blockIdx.x;
    const int wk = (dd & 7) * q8 + (dd >> 3);
    const int bm = (wk % Mt) * 256;
    const int bn = (wk / Mt) * 256;
    const int tid = threadIdx.x;
    const int lane = tid & 63;
    const int wid = tid >> 6;
    const int wm = wid >> 2, wn = wid & 3;
    const int r15 = lane & 15, hi16 = lane >> 4;

    f32x4 acc[8][4];
#pragma unroll
    for (int mi = 0; mi < 8; ++mi)
#pragma unroll
        for (int ni = 0; ni < 4; ++ni) acc[mi][ni] = (f32x4){0.f, 0.f, 0.f, 0.f};

    // A staging (identical geometry to gemm256)
    const int rpl  = lane >> 3;
    const int ch8d = (lane & 7) ^ rpl;
    const int srA  = wid * 16 + rpl * 2 + (ch8d >> 2);
    const int skA  = (ch8d & 3) * 8;
    const int ldst = wid * 512;

    // B reg staging: 1024 16B-chunks; thread handles c = tid, tid+512.
    // chunk at (rp,slot) holds data chunk ch8 = slot ^ (rp&7):
    // source row = 2*rp + (ch8>>2), k-offset = (ch8&3)*8.
    int rpB[2], slB[2], srB[2], skB[2];
#pragma unroll
    for (int i = 0; i < 2; ++i) {
        const int c = tid + i * 512;
        rpB[i] = c >> 3; slB[i] = c & 7;
        const int ch8 = slB[i] ^ (rpB[i] & 7);
        srB[i] = rpB[i] * 2 + (ch8 >> 2);
        skB[i] = (ch8 & 3) * 8;
    }

    const int nt = K / 32;
    float4 f0[2], f1[2];
    {   // prologue: tile 0 -> buf 0
        ldsload16(&A[(size_t)(bm + srA)       * K + skA], &As[0][ldst]);
        ldsload16(&A[(size_t)(bm + 128 + srA) * K + skA], &As[0][4096 + ldst]);
#pragma unroll
        for (int i = 0; i < 2; ++i) {
            f0[i] = *(const float4*)&Bf[(size_t)(bn + srB[i]) * K + skB[i]];
            f1[i] = *(const float4*)&Bf[(size_t)(bn + srB[i]) * K + skB[i] + 4];
        }
#pragma unroll
        for (int i = 0; i < 2; ++i) {
            uint4 p;
            p.x = (unsigned)f2h(f0[i].x) | ((unsigned)f2h(f0[i].y) << 16);
            p.y = (unsigned)f2h(f0[i].z) | ((unsigned)f2h(f0[i].w) << 16);
            p.z = (unsigned)f2h(f1[i].x) | ((unsigned)f2h(f1[i].y) << 16);
            p.w = (unsigned)f2h(f1[i].z) | ((unsigned)f2h(f1[i].w) << 16);
            *(uint4*)&Bs[0][rpB[i] * 64 + slB[i] * 8] = p;
        }
    }
    __syncthreads();

    for (int t = 0; t < nt; ++t) {
        const int cur = t & 1;
        const int nb = cur ^ 1;
        if (t + 1 < nt) {   // issue next-tile loads (A -> LDS, B -> regs)
            const size_t k0 = (size_t)(t + 1) * 32;
            ldsload16(&A[(size_t)(bm + srA)       * K + k0 + skA], &As[nb][ldst]);
            ldsload16(&A[(size_t)(bm + 128 + srA) * K + k0 + skA], &As[nb][4096 + ldst]);
#pragma unroll
            for (int i = 0; i < 2; ++i) {
                f0[i] = *(const float4*)&Bf[(size_t)(bn + srB[i]) * K + k0 + skB[i]];
                f1[i] = *(const float4*)&Bf[(size_t)(bn + srB[i]) * K + k0 + skB[i] + 4];
            }
        }
        const u16* Ab = As[cur];
        const u16* Bb = Bs[cur];
        f16x8 bf[4], af[8];
#pragma unroll
        for (int ni = 0; ni < 4; ++ni) {
            const int row = wn * 64 + ni * 16 + r15;
            const int rp = row >> 1;
            const int slot = (((row & 1) << 2) | hi16) ^ (rp & 7);
            bf[ni] = *(const f16x8*)&Bb[rp * 64 + slot * 8];
        }
#pragma unroll
        for (int mi = 0; mi < 8; ++mi) {
            const int row = wm * 128 + mi * 16 + r15;
            const int rp = row >> 1;
            const int slot = (((row & 1) << 2) | hi16) ^ (rp & 7);
            af[mi] = *(const f16x8*)&Ab[rp * 64 + slot * 8];
        }
        __builtin_amdgcn_s_setprio(1);
#pragma unroll
        for (int mi = 0; mi < 8; ++mi)
#pragma unroll
            for (int ni = 0; ni < 4; ++ni)
                acc[mi][ni] = __builtin_amdgcn_mfma_f32_16x16x32_f16(af[mi], bf[ni], acc[mi][ni], 0, 0, 0);
        __builtin_amdgcn_s_setprio(0);
        if (t + 1 < nt) {   // B values arrived during MFMA; write to free buffer
#pragma unroll
            for (int i = 0; i < 2; ++i) {
                uint4 p;
                p.x = (unsigned)f2h(f0[i].x) | ((unsigned)f2h(f0[i].y) << 16);
                p.y = (unsigned)f2h(f0[i].z) | ((unsigned)f2h(f0[i].w) << 16);
                p.z = (unsigned)f2h(f1[i].x) | ((unsigned)f2h(f1[i].y) << 16);
                p.w = (unsigned)f2h(f1[i].z) | ((unsigned)f2h(f1[i].w) << 16);
                *(uint4*)&Bs[nb][rpB[i] * 64 + slB[i] * 8] = p;
            }
        }
        __syncthreads();   // A gload + B ds_writes complete; reads consumed
    }

#pragma unroll
    for (int mi = 0; mi < 8; ++mi)
#pragma unroll
        for (int ni = 0; ni < 4; ++ni)
#pragma unroll
            for (int r = 0; r < 4; ++r) {
                const int row = bm + wm * 128 + mi * 16 + hi16 * 4 + r;
                const int col = bn + wn * 64 + ni * 16 + r15;
                Cout[(size_t)row * ldc + col] = acc[mi][ni][r];
            }
}

// ---------------------------------------------------------------------------
// batched QK^T scores (fp16): Sc[bh][q][k] fp32.  BK=64, swzK, tile skip.
// ---------------------------------------------------------------------------
__global__ __launch_bounds__(256) void qk_f16(const u16* __restrict__ Qh,
                                              const u16* __restrict__ Kh,
                                              float* __restrict__ Sc,
                                              int HDIM, int KVH, int win) {
    const int bm = blockIdx.y * 128;   // q tile
    const int bn = blockIdx.x * 128;   // k tile
    if (bn > bm + 127) return;
    if (win > 0 && bm - bn > win + 126) return;
    const int bh = blockIdx.z;
    const int b = bh / cH, h = bh % cH;
    const int kh = h / (cH / KVH);

    __shared__ u16 As[128 * 64];
    __shared__ u16 Bs[128 * 64];
    const int tid = threadIdx.x;
    const int lane = tid & 63;
    const int w = tid >> 6;
    const int wr = (w >> 1) * 64, wc = (w & 1) * 64;
    const int r15 = lane & 15, hi16 = lane >> 4;

    const int lda = cH * HDIM, ldb = KVH * HDIM;
    const u16* Aq = Qh + ((size_t)b * cS * cH + h) * HDIM;
    const u16* Bk = Kh + ((size_t)b * cS * KVH + kh) * HDIM;

    f32x4 acc[4][4];
#pragma unroll
    for (int m = 0; m < 4; ++m)
#pragma unroll
        for (int n = 0; n < 4; ++n) acc[m][n] = (f32x4){0.f, 0.f, 0.f, 0.f};

    int rA[4], cA[4], wl[4];
#pragma unroll
    for (int j = 0; j < 4; ++j) {
        const int c = tid + j * 256;
        rA[j] = c >> 3; cA[j] = (c & 7) * 8;
        wl[j] = swzK(rA[j], c & 7);
    }

    for (int k0 = 0; k0 < HDIM; k0 += 64) {
        uint4 av[4], bv[4];
#pragma unroll
        for (int j = 0; j < 4; ++j) {
            av[j] = *(const uint4*)&Aq[(size_t)(bm + rA[j]) * lda + k0 + cA[j]];
            bv[j] = *(const uint4*)&Bk[(size_t)(bn + rA[j]) * ldb + k0 + cA[j]];
        }
        __syncthreads();
#pragma unroll
        for (int j = 0; j < 4; ++j) {
            *(uint4*)&As[wl[j]] = av[j];
            *(uint4*)&Bs[wl[j]] = bv[j];
        }
        __syncthreads();
#pragma unroll
        for (int kk = 0; kk < 2; ++kk) {
            f16x8 af[4], bf4[4];
#pragma unroll
            for (int m = 0; m < 4; ++m)
                af[m] = *(const f16x8*)&As[swzK(wr + m * 16 + r15, kk * 4 + hi16)];
#pragma unroll
            for (int n = 0; n < 4; ++n)
                bf4[n] = *(const f16x8*)&Bs[swzK(wc + n * 16 + r15, kk * 4 + hi16)];
#pragma unroll
            for (int m = 0; m < 4; ++m)
#pragma unroll
                for (int n = 0; n < 4; ++n)
                    acc[m][n] = __builtin_amdgcn_mfma_f32_16x16x32_f16(af[m], bf4[n], acc[m][n], 0, 0, 0);
        }
    }
    float* Crow = Sc + (size_t)bh * cS * cS;
#pragma unroll
    for (int m = 0; m < 4; ++m)
#pragma unroll
        for (int n = 0; n < 4; ++n)
#pragma unroll
            for (int r = 0; r < 4; ++r)
                Crow[(size_t)(bm + wr + m * 16 + hi16 * 4 + r) * cS + bn + wc + n * 16 + r15]
                    = acc[m][n][r];
}

// ---------------------------------------------------------------------------
// row softmax over fp32 scores, in-place rewrite as fp16 P (row prefix).
// ---------------------------------------------------------------------------
__global__ __launch_bounds__(256) void softmax_kernel(float* __restrict__ Sc,
                                                      const int* __restrict__ tlen,
                                                      int win) {
    const int q = blockIdx.x, bh = blockIdx.y, b = bh / cH;
    float* row = Sc + ((size_t)bh * cS + q) * cS;
    u16* rowh = (u16*)row;
    const int tid = threadIdx.x;
    const int tl = tlen[b];
    const int kmax = min(q, tl - 1);
    const int kmin = (win > 0) ? max(0, q - win + 1) : 0;

    float v[4];
    float m = -1e30f;
#pragma unroll
    for (int j = 0; j < 4; ++j) {
        const int k = tid + j * 256;
        const bool ok = (k >= kmin && k <= kmax);
        v[j] = ok ? row[k] : -1e30f;
        m = fmaxf(m, v[j]);
    }
    for (int o = 32; o >= 1; o >>= 1) m = fmaxf(m, __shfl_xor(m, o));
    __shared__ float rb[8];
    if ((tid & 63) == 0) rb[tid >> 6] = m;
    __syncthreads();
    m = fmaxf(fmaxf(rb[0], rb[1]), fmaxf(rb[2], rb[3]));

    float e[4];
    float s = 0.f;
#pragma unroll
    for (int j = 0; j < 4; ++j) {
        const int k = tid + j * 256;
        const bool ok = (k >= kmin && k <= kmax);
        e[j] = ok ? expf(v[j] - m) : 0.f;
        s += e[j];
    }
    for (int o = 32; o >= 1; o >>= 1) s += __shfl_xor(s, o);
    __shared__ float sb[4];
    if ((tid & 63) == 0) sb[tid >> 6] = s;
    __syncthreads();
    s = sb[0] + sb[1] + sb[2] + sb[3];
    const float inv = 1.f / s;
    __syncthreads();   // fp32 reads complete before u16 overwrite
#pragma unroll
    for (int j = 0; j < 4; ++j) {
        const int k = tid + j * 256;
        rowh[k] = f2h(e[j] * inv);
    }
}

// ---------------------------------------------------------------------------
// batched PV (fp16): O[b,q,h*HDIM+d] = P[bh] @ Vt[b,kh]. BK=64, swzK.
// ---------------------------------------------------------------------------
__global__ __launch_bounds__(256) void pv_f16(const u16* __restrict__ P,
                                              const u16* __restrict__ Vt,
                                              u16* __restrict__ O,
                                              int HDIM, int KVH, int win) {
    const int bh = blockIdx.z;
    const int b = bh / cH, h = bh % cH;
    const int kh = h / (cH / KVH);
    const int bm = blockIdx.y * 128;   // q tile
    const int bn = blockIdx.x * 128;   // d tile

    __shared__ u16 As[128 * 64];
    __shared__ u16 Bs[128 * 64];
    const int tid = threadIdx.x;
    const int lane = tid & 63;
    const int w = tid >> 6;
    const int wr = (w >> 1) * 64, wc = (w & 1) * 64;
    const int r15 = lane & 15, hi16 = lane >> 4;

    const u16* Ap = P + (size_t)bh * cS * 2048;
    const u16* Bv = Vt + ((size_t)b * KVH + kh) * HDIM * cS;

    f32x4 acc[4][4];
#pragma unroll
    for (int m = 0; m < 4; ++m)
#pragma unroll
        for (int n = 0; n < 4; ++n) acc[m][n] = (f32x4){0.f, 0.f, 0.f, 0.f};

    int rA[4], cA[4], wl[4];
#pragma unroll
    for (int j = 0; j < 4; ++j) {
        const int c = tid + j * 256;
        rA[j] = c >> 3; cA[j] = (c & 7) * 8;
        wl[j] = swzK(rA[j], c & 7);
    }

    const int klo = (win > 0) ? (max(0, bm - win + 1) & ~63) : 0;
    const int khi = min(bm + 128, cS);

    for (int k0 = klo; k0 < khi; k0 += 64) {
        uint4 av[4], bv[4];
#pragma unroll
        for (int j = 0; j < 4; ++j) {
            av[j] = *(const uint4*)&Ap[(size_t)(bm + rA[j]) * 2048 + k0 + cA[j]];
            bv[j] = *(const uint4*)&Bv[(size_t)(bn + rA[j]) * cS + k0 + cA[j]];
        }
        __syncthreads();
#pragma unroll
        for (int j = 0; j < 4; ++j) {
            *(uint4*)&As[wl[j]] = av[j];
            *(uint4*)&Bs[wl[j]] = bv[j];
        }
        __syncthreads();
#pragma unroll
        for (int kk = 0; kk < 2; ++kk) {
            f16x8 af[4], bf4[4];
#pragma unroll
            for (int m = 0; m < 4; ++m)
                af[m] = *(const f16x8*)&As[swzK(wr + m * 16 + r15, kk * 4 + hi16)];
#pragma unroll
            for (int n = 0; n < 4; ++n)
                bf4[n] = *(const f16x8*)&Bs[swzK(wc + n * 16 + r15, kk * 4 + hi16)];
#pragma unroll
            for (int m = 0; m < 4; ++m)
#pragma unroll
                for (int n = 0; n < 4; ++n)
                    acc[m][n] = __builtin_amdgcn_mfma_f32_16x16x32_f16(af[m], bf4[n], acc[m][n], 0, 0, 0);
        }
    }
    const int ldo = cH * HDIM;
#pragma unroll
    for (int m = 0; m < 4; ++m)
#pragma unroll
        for (int n = 0; n < 4; ++n)
#pragma unroll
            for (int r = 0; r < 4; ++r) {
                const int q = bm + wr + m * 16 + hi16 * 4 + r;
                const int d = bn + wc + n * 16 + r15;
                O[(size_t)(b * cS + q) * ldo + h * HDIM + d] = f2h(acc[m][n][r]);
            }
}

// ---------------------------------------------------------------------------
extern "C" void kernel_launch(void* const* d_in, const int* in_sizes, int n_in,
                              void* d_out, int out_size, void* d_ws, size_t ws_size,
                              hipStream_t stream) {
    (void)in_sizes; (void)n_in; (void)out_size; (void)ws_size;
    const int*   tokens = (const int*)  d_in[0];
    const int*   tlen   = (const int*)  d_in[1];
    const float* embed  = (const float*)d_in[2];
    const float* norm_w = (const float*)d_in[3];
    const float* s_wq   = (const float*)d_in[4];
    const float* s_wk   = (const float*)d_in[5];
    const float* s_wv   = (const float*)d_in[6];
    const float* s_wo   = (const float*)d_in[7];
    const float* s_qn   = (const float*)d_in[8];
    const float* s_kn   = (const float*)d_in[9];
    const float* s_wg   = (const float*)d_in[10];
    const float* s_wu   = (const float*)d_in[11];
    const float* s_wd   = (const float*)d_in[12];
    const float* s_ln1  = (const float*)d_in[13];
    const float* s_ln2  = (const float*)d_in[14];
    const float* s_ln3  = (const float*)d_in[15];
    const float* s_ln4  = (const float*)d_in[16];
    const float* s_scal = (const float*)d_in[17];
    const float* g_wq   = (const float*)d_in[18];
    const float* g_wk   = (const float*)d_in[19];
    const float* g_wo   = (const float*)d_in[20];
    const float* g_qn   = (const float*)d_in[21];
    const float* g_kn   = (const float*)d_in[22];
    const float* g_wg   = (const float*)d_in[23];
    const float* g_wu   = (const float*)d_in[24];
    const float* g_wd   = (const float*)d_in[25];
    const float* g_ln1  = (const float*)d_in[26];
    const float* g_ln2  = (const float*)d_in[27];
    const float* g_ln3  = (const float*)d_in[28];
    const float* g_ln4  = (const float*)d_in[29];
    const float* g_scal = (const float*)d_in[30];

    // workspace (peak <156 MiB), phase-disjoint (same plan as round 13)
    char* w8 = (char*)d_ws;
    float* x   = (float*)(w8);
    u16*   ab  = (u16*)(w8 + 16 * MB);
    u16*   wp  = (u16*)(w8 + 24 * MB);
    u16*   Qb  = (u16*)(w8 + 24 * MB);
    u16*   Ob  = (u16*)(w8 + 24 * MB);
    u16*   t0b = (u16*)(w8 + 56 * MB);
    u16*   Kb  = (u16*)(w8 + 58 * MB);
    u16*   Vt  = (u16*)(w8 + 75 * MB);
    float* qkg = (float*)(w8 + 84 * MB);
    float* scores = (float*)(w8 + 84 * MB);
    u16*   Pb  = (u16*)(w8 + 84 * MB);
    u16*   wo2 = (u16*)(w8 + 84 * MB);
    u16*   t1b = (u16*)(w8 + 88 * MB);
    float* r0  = (float*)(w8 + 116 * MB);
    float* fo  = (float*)(w8 + 120 * MB);
    float* vf  = (float*)(w8 + 132 * MB);

    auto tcast = [&](const float* in, u16* outp, int K, int N, int ldin) {
        tcast_kernel<<<dim3(N / 32, K / 32), 256, 0, stream>>>(in, outp, K, N, ldin);
    };
    auto gemmF = [&](const u16* A, const u16* Bt, float* C, int N, int K, int ldc) {
        gemm_f16<false, false><<<16 * (N / 128), 256, 0, stream>>>(A, Bt, C, nullptr, 16, K, ldc);
    };
    auto g256H = [&](const u16* A, const u16* Bt, u16* C, int N, int K, int ldc) {
        gemm256<true, false><<<8 * (N / 256), 512, 0, stream>>>(A, Bt, C, nullptr, 8, K, ldc);
    };
    auto g256HG = [&](const u16* A, const u16* Bt, u16* C, const u16* gate,
                      int N, int K, int ldc) {
        gemm256<true, true><<<8 * (N / 256), 512, 0, stream>>>(A, Bt, C, gate, 8, K, ldc);
    };

    // attention core: Qb/Kb fp16 + vf fp32 (dense) ready; writes Ob fp16
    auto attention = [&](int HDIM, int KVH, int win) {
        vtrans_kernel<<<dim3(HDIM / 32, cS / 32, cB * KVH), 256, 0, stream>>>(vf, Vt, HDIM, KVH);
        qk_f16<<<dim3(cS / 128, cS / 128, cB * cH), 256, 0, stream>>>(
            Qb, Kb, scores, HDIM, KVH, win);
        softmax_kernel<<<dim3(cS, cB * cH), 256, 0, stream>>>(scores, tlen, win);
        pv_f16<<<dim3(HDIM / 128, cS / 128, cB * cH), 256, 0, stream>>>(
            Pb, Vt, Ob, HDIM, KVH, win);
    };

    embed_kernel<<<cM, 256, 0, stream>>>(tokens, embed, x);

    // ================= block 1: sliding-window =================
    rms_f16_kernel<<<cM, 256, 0, stream>>>(x, s_ln1, ab, cD);
    tcast(s_wq, wp, cD, cH * cHD, cH * cHD);
    tcast(s_wk, wp + (size_t)2048 * cD, cD, cKV * cHD, cKV * cHD);
    tcast(s_wv, wp + (size_t)3072 * cD, cD, cKV * cHD, cKV * cHD);
    gemmF(ab, wp, qkg, 4096, cD, 4096);                               // [M,4096] q|k|v
    rms_kernel<<<cM * cKV, 256, 0, stream>>>(qkg + 3072, nullptr, vf, cHD, 4096, cKV);
    rmsrope_kernel<<<cM * cH, 128, 0, stream>>>(qkg, s_qn, Qb, cH, cHD, cHD, 10000.f, 4096);
    rmsrope_kernel<<<cM * cKV, 128, 0, stream>>>(qkg + 2048, s_kn, Kb, cKV, cHD, cHD, 10000.f, 4096);
    attention(cHD, cKV, cWIN);
    tcast(s_wo, wo2, cH * cHD, cD, cD);
    gemmF(Ob, wo2, r0, cD, cH * cHD, cD);
    addnorm_kernel<<<cM, 256, 0, stream>>>(x, r0, s_ln2, nullptr, s_ln3, x, ab);
    tcast(s_wg, wp, cD, cF, cF);
    g256H(ab, wp, t1b, cF, cD, cF);                 // gate -> t1b
    tcast(s_wu, wp, cD, cF, cF);
    g256HG(ab, wp, t0b, t1b, cF, cD, cF);           // gelu(gate)*up -> t0b
    tcast(s_wd, wp, cF, cD, cD);
    gemmF(t0b, wp, fo, cD, cF, cD);
    addnorm_kernel<<<cM, 256, 0, stream>>>(x, fo, s_ln4, s_scal, g_ln1, x, ab);

    // ================= block 2: global =================
    tcast(g_wq, wp, cD, cH * cGHD, cH * cGHD);
    tcast(g_wk, wp + (size_t)4096 * cD, cD, cGKV * cGHD, cGKV * cGHD);
    gemmF(ab, wp, qkg, 6144, cD, 6144);                               // [M,6144] q|k
    rms_kernel<<<cM * cGKV, 256, 0, stream>>>(qkg + 4096, nullptr, vf, cGHD, 6144, cGKV);
    rmsrope_kernel<<<cM * cH, 128, 0, stream>>>(qkg, g_qn, Qb, cH, cGHD, cROT, 1000000.f, 6144);
    rmsrope_kernel<<<cM * cGKV, 128, 0, stream>>>(qkg + 4096, g_kn, Kb, cGKV, cGHD, cROT, 1000000.f, 6144);
    attention(cGHD, cGKV, 0);
    tcast(g_wo, wo2, cH * cGHD, cD, cD);
    gemmF(Ob, wo2, r0, cD, cH * cGHD, cD);
    addnorm_kernel<<<cM, 256, 0, stream>>>(x, r0, g_ln2, nullptr, g_ln3, x, ab);
    tcast(g_wg, wp, cD, cF, cF);
    g256H(ab, wp, t1b, cF, cD, cF);
    tcast(g_wu, wp, cD, cF, cF);
    g256HG(ab, wp, t0b, t1b, cF, cD, cF);
    tcast(g_wd, wp, cF, cD, cD);
    gemmF(t0b, wp, fo, cD, cF, cD);
    addnorm_kernel<<<cM, 256, 0, stream>>>(x, fo, g_ln4, g_scal, norm_w, x, ab);

    // ================= logits: fp32-B direct 256^2 GEMM (no cast pass) ======
    gemm_logits256<<<8 * (cV / 256), 512, 0, stream>>>(
        ab, embed, (float*)d_out, 8, cD, cV);
}

// Round 15
// 1942.359 us; speedup vs baseline: 1.0551x; 1.0551x over previous
//
#include <hip/hip_runtime.h>
#include <math.h>

typedef unsigned short u16;
typedef _Float16 f16;
typedef __attribute__((ext_vector_type(8))) _Float16 f16x8;
typedef __attribute__((ext_vector_type(4))) float f32x4;

// ---- problem constants ----
constexpr int cB   = 2;
constexpr int cS   = 1024;
constexpr int cD   = 2048;
constexpr int cH   = 8;
constexpr int cHD  = 256;
constexpr int cKV  = 4;
constexpr int cGHD = 512;
constexpr int cGKV = 4;
constexpr int cROT = 128;
constexpr int cF   = 8192;
constexpr int cV   = 32000;
constexpr int cWIN = 512;
constexpr int cM   = cB * cS;   // 2048 token rows
constexpr float cEPS = 1e-6f;
constexpr size_t MB = 1024 * 1024;

__device__ inline u16 f2h(float x) { union { f16 h; u16 u; } c; c.h = (f16)x; return c.u; }
__device__ inline float h2f(u16 v) { union { u16 u; f16 h; } c; c.u = v; return (float)c.h; }

// swizzled LDS u16-index: [128][32] u16 rows, 16B chunks XOR'd by (row>>1)&3.
__device__ inline int swz16(int row, int chunk) {
    return row * 32 + ((chunk ^ ((row >> 1) & 3)) << 3);
}
// swizzle for BK=64 fp16 arrays (qk/pv): [row][64] u16, 16B chunk ^= row&7
__device__ inline int swzK(int row, int ch) {
    return row * 64 + ((ch ^ (row & 7)) << 3);
}

// async 16B global->LDS (wave-uniform LDS base + lane*16; per-lane global addr)
typedef __attribute__((address_space(1))) const unsigned int gu32;
typedef __attribute__((address_space(3))) unsigned int lu32;
__device__ inline void ldsload16(const u16* g, u16* l) {
    __builtin_amdgcn_global_load_lds((gu32*)g, (lu32*)l, 16, 0, 0);
}

__device__ inline float gelu_tanh(float v) {
    const float t = tanhf(0.7978845608028654f * (v + 0.044715f * v * v * v));
    return 0.5f * v * (1.f + t);
}

// ---------------------------------------------------------------------------
// embed lookup * sqrt(D)
// ---------------------------------------------------------------------------
__global__ void embed_kernel(const int* __restrict__ tok,
                             const float* __restrict__ emb,
                             float* __restrict__ out) {
    const int row = blockIdx.x;
    const int t = tok[row];
    const float* e = emb + (size_t)t * cD;
    float* o = out + (size_t)row * cD;
    const float sc = sqrtf((float)cD);
    for (int d = threadIdx.x; d < cD; d += blockDim.x) o[d] = e[d] * sc;
}

// ---------------------------------------------------------------------------
// row RMS norm fp32->fp32.  Input rows may live in a wider matrix:
// in offset = (row/nh)*xld + (row%nh)*dim ; output is dense (row*dim).
// ---------------------------------------------------------------------------
__global__ void rms_kernel(const float* __restrict__ x,
                           const float* __restrict__ w,
                           float* __restrict__ out, int dim, int xld, int nh) {
    const int row = blockIdx.x;
    const float* xr = x + (size_t)(row / nh) * xld + (size_t)(row % nh) * dim;
    float* orow = out + (size_t)row * dim;
    float ss = 0.f;
    for (int d = threadIdx.x; d < dim; d += blockDim.x) { float v = xr[d]; ss += v * v; }
    for (int o = 32; o >= 1; o >>= 1) ss += __shfl_xor(ss, o);
    __shared__ float rb[8];
    if ((threadIdx.x & 63) == 0) rb[threadIdx.x >> 6] = ss;
    __syncthreads();
    ss = rb[0] + rb[1] + rb[2] + rb[3];
    const float r = rsqrtf(ss / dim + cEPS);
    for (int d = threadIdx.x; d < dim; d += blockDim.x)
        orow[d] = xr[d] * r * (w ? w[d] : 1.f);
}

// row RMS norm fp32 -> fp16 (dense both sides)
__global__ void rms_f16_kernel(const float* __restrict__ x,
                               const float* __restrict__ w,
                               u16* __restrict__ out, int dim) {
    const int row = blockIdx.x;
    const float* xr = x + (size_t)row * dim;
    u16* orow = out + (size_t)row * dim;
    float ss = 0.f;
    for (int d = threadIdx.x; d < dim; d += blockDim.x) { float v = xr[d]; ss += v * v; }
    for (int o = 32; o >= 1; o >>= 1) ss += __shfl_xor(ss, o);
    __shared__ float rb[8];
    if ((threadIdx.x & 63) == 0) rb[threadIdx.x >> 6] = ss;
    __syncthreads();
    ss = rb[0] + rb[1] + rb[2] + rb[3];
    const float r = rsqrtf(ss / dim + cEPS);
    for (int d = threadIdx.x; d < dim; d += blockDim.x)
        orow[d] = f2h(xr[d] * r * (w ? w[d] : 1.f));
}

// ---------------------------------------------------------------------------
// fused: x_new = (res + y*rms(y)*w_add) * scal ; ab = fp16(x_new*rms(x_new)*w_norm)
// ---------------------------------------------------------------------------
__global__ __launch_bounds__(256) void addnorm_kernel(const float* __restrict__ res,
                                                      const float* __restrict__ y,
                                                      const float* __restrict__ w_add,
                                                      const float* __restrict__ scal,
                                                      const float* __restrict__ w_norm,
                                                      float* __restrict__ xout,
                                                      u16* __restrict__ abo) {
    const int row = blockIdx.x;
    const float* yr = y + (size_t)row * cD;
    const float* rr = res + (size_t)row * cD;
    float* xo = xout + (size_t)row * cD;
    u16* ao = abo + (size_t)row * cD;
    const int tid = threadIdx.x;
    __shared__ float rb[4];

    float yl[8], xl[8];
    float ss = 0.f;
#pragma unroll
    for (int j = 0; j < 8; ++j) { yl[j] = yr[tid + j * 256]; ss += yl[j] * yl[j]; }
    for (int o = 32; o >= 1; o >>= 1) ss += __shfl_xor(ss, o);
    if ((tid & 63) == 0) rb[tid >> 6] = ss;
    __syncthreads();
    ss = rb[0] + rb[1] + rb[2] + rb[3];
    const float r1 = rsqrtf(ss / cD + cEPS);
    const float sc = scal ? *scal : 1.f;

    float ss2 = 0.f;
#pragma unroll
    for (int j = 0; j < 8; ++j) {
        const int d = tid + j * 256;
        xl[j] = (rr[d] + yl[j] * r1 * w_add[d]) * sc;
        ss2 += xl[j] * xl[j];
    }
    for (int o = 32; o >= 1; o >>= 1) ss2 += __shfl_xor(ss2, o);
    __syncthreads();
    if ((tid & 63) == 0) rb[tid >> 6] = ss2;
    __syncthreads();
    ss2 = rb[0] + rb[1] + rb[2] + rb[3];
    const float r2 = rsqrtf(ss2 / cD + cEPS);
#pragma unroll
    for (int j = 0; j < 8; ++j) {
        const int d = tid + j * 256;
        xo[d] = xl[j];
        ao[d] = f2h(xl[j] * r2 * w_norm[d]);
    }
}

// ---------------------------------------------------------------------------
// fused: rms(x)*w -> partial rope -> fp16.  one block (128 thr) per head-row.
// input offset = (row/NH)*xld + (row%NH)*HDIM ; out dense row*HDIM.
// ---------------------------------------------------------------------------
__global__ __launch_bounds__(128) void rmsrope_kernel(const float* __restrict__ x,
                                                      const float* __restrict__ w,
                                                      u16* __restrict__ out,
                                                      int NH, int HDIM, int rot,
                                                      float theta, int xld) {
    const int row = blockIdx.x;
    const int s = (row / NH) % cS;
    const float* xr = x + (size_t)(row / NH) * xld + (size_t)(row % NH) * HDIM;
    u16* orow = out + (size_t)row * HDIM;
    const int tid = threadIdx.x;
    const int np = HDIM >> 1;
    __shared__ float rb[2];

    float v1[2], v2[2];
    float ss = 0.f;
    for (int p = tid, j = 0; p < np; p += 128, ++j) {
        v1[j] = xr[2 * p]; v2[j] = xr[2 * p + 1];
        ss += v1[j] * v1[j] + v2[j] * v2[j];
    }
    for (int o = 32; o >= 1; o >>= 1) ss += __shfl_xor(ss, o);
    if ((tid & 63) == 0) rb[tid >> 6] = ss;
    __syncthreads();
    ss = rb[0] + rb[1];
    const float r = rsqrtf(ss / HDIM + cEPS);
    const int halfrot = rot >> 1;
    for (int p = tid, j = 0; p < np; p += 128, ++j) {
        const float a = v1[j] * r * w[2 * p];
        const float b = v2[j] * r * w[2 * p + 1];
        float o1 = a, o2 = b;
        if (p < halfrot) {
            const float inv = powf(theta, -(2.f * p) / (float)rot);
            const float ang = (float)s * inv;
            const float c = cosf(ang), sn = sinf(ang);
            o1 = a * c - b * sn;
            o2 = a * sn + b * c;
        }
        orow[2 * p]     = f2h(o1);
        orow[2 * p + 1] = f2h(o2);
    }
}

// ---------------------------------------------------------------------------
// fp32 [K][N] (row stride ldin) -> fp16 [N][K]
// ---------------------------------------------------------------------------
__global__ __launch_bounds__(256) void tcast_kernel(const float* __restrict__ in,
                                                    u16* __restrict__ out,
                                                    int K, int N, int ldin) {
    __shared__ float t[32][33];
    const int kt = blockIdx.y * 32, nt = blockIdx.x * 32;
    const int tx = threadIdx.x & 31, ty = threadIdx.x >> 5;   // ty 0..7
#pragma unroll
    for (int j = 0; j < 4; ++j)
        t[ty + j * 8][tx] = in[(size_t)(kt + ty + j * 8) * ldin + nt + tx];
    __syncthreads();
#pragma unroll
    for (int j = 0; j < 4; ++j)
        out[(size_t)(nt + ty + j * 8) * K + kt + tx] = f2h(t[tx][ty + j * 8]);
}

// fp32 -> fp16 elementwise (4 per thread)
__global__ void cast_f16_kernel(const float* __restrict__ in, u16* __restrict__ out,
                                int n) {
    const int i = blockIdx.x * blockDim.x + threadIdx.x;
    if (i * 4 >= n) return;
    const float4 v = *(const float4*)&in[(size_t)i * 4];
    uint2 o;
    o.x = (unsigned)f2h(v.x) | ((unsigned)f2h(v.y) << 16);
    o.y = (unsigned)f2h(v.z) | ((unsigned)f2h(v.w) << 16);
    *(uint2*)&out[(size_t)i * 4] = o;
}

// V fp32 [B,S,KVH,HDIM] dense -> Vt fp16 [B*KVH, HDIM, S]
__global__ __launch_bounds__(256) void vtrans_kernel(const float* __restrict__ V,
                                                     u16* __restrict__ Vt,
                                                     int HDIM, int KVH) {
    __shared__ float t[32][33];
    const int bk = blockIdx.z;
    const int b = bk / KVH, kh = bk % KVH;
    const int st = blockIdx.y * 32, dt = blockIdx.x * 32;
    const int tx = threadIdx.x & 31, ty = threadIdx.x >> 5;
#pragma unroll
    for (int j = 0; j < 4; ++j)
        t[ty + j * 8][tx] = V[((size_t)(b * cS + st + ty + j * 8) * KVH + kh) * HDIM + dt + tx];
    __syncthreads();
#pragma unroll
    for (int j = 0; j < 4; ++j)
        Vt[((size_t)bk * HDIM + dt + ty + j * 8) * cS + st + tx] = f2h(t[tx][ty + j * 8]);
}

// ---------------------------------------------------------------------------
// fp16 MFMA GEMM (m97 structure, 128x128, BK=32): for small-N GEMMs.
// ---------------------------------------------------------------------------
template<bool F16_OUT, bool GELU>
__global__ __launch_bounds__(256) void gemm_f16(const u16* __restrict__ A,
                                                const u16* __restrict__ Bt,
                                                void* __restrict__ Cout,
                                                const u16* __restrict__ gate,
                                                int Mt, int K, int ldc) {
    __shared__ u16 As[128 * 32];
    __shared__ u16 Bs[128 * 32];
    const int nwg = gridDim.x;
    const int q8 = nwg >> 3;
    const int dd = blockIdx.x;
    const int wk = (dd & 7) * q8 + (dd >> 3);       // bijective XCD-contiguous
    const int bm = (wk % Mt) * 128;
    const int bn = (wk / Mt) * 128;
    const int tid = threadIdx.x;
    const int lane = tid & 63;
    const int wv = tid >> 6;
    const int wr = (wv >> 1) * 64, wc = (wv & 1) * 64;
    const int r15 = lane & 15, hi16 = lane >> 4;

    f32x4 acc[4][4];
#pragma unroll
    for (int m = 0; m < 4; ++m)
#pragma unroll
        for (int n = 0; n < 4; ++n) acc[m][n] = (f32x4){0.f, 0.f, 0.f, 0.f};

    int rowS[2], koS[2];
#pragma unroll
    for (int i = 0; i < 2; ++i) {
        const int s = i * 256 + tid;
        rowS[i] = s >> 2;
        koS[i] = ((s & 3) ^ ((rowS[i] >> 1) & 3)) * 8;
    }
    u16* ldsA0 = &As[(wv * 64) * 8];
    u16* ldsA1 = &As[(256 + wv * 64) * 8];
    u16* ldsB0 = &Bs[(wv * 64) * 8];
    u16* ldsB1 = &Bs[(256 + wv * 64) * 8];

    for (int k0 = 0; k0 < K; k0 += 32) {
        __syncthreads();
        ldsload16(&A [(size_t)(bm + rowS[0]) * K + k0 + koS[0]], ldsA0);
        ldsload16(&A [(size_t)(bm + rowS[1]) * K + k0 + koS[1]], ldsA1);
        ldsload16(&Bt[(size_t)(bn + rowS[0]) * K + k0 + koS[0]], ldsB0);
        ldsload16(&Bt[(size_t)(bn + rowS[1]) * K + k0 + koS[1]], ldsB1);
        __syncthreads();
        f16x8 af[4], bf4[4];
#pragma unroll
        for (int m = 0; m < 4; ++m)
            af[m] = *(const f16x8*)&As[swz16(wr + m * 16 + r15, hi16)];
#pragma unroll
        for (int n = 0; n < 4; ++n)
            bf4[n] = *(const f16x8*)&Bs[swz16(wc + n * 16 + r15, hi16)];
#pragma unroll
        for (int m = 0; m < 4; ++m)
#pragma unroll
            for (int n = 0; n < 4; ++n)
                acc[m][n] = __builtin_amdgcn_mfma_f32_16x16x32_f16(af[m], bf4[n], acc[m][n], 0, 0, 0);
    }
#pragma unroll
    for (int m = 0; m < 4; ++m)
#pragma unroll
        for (int n = 0; n < 4; ++n)
#pragma unroll
            for (int r = 0; r < 4; ++r) {
                const int row = bm + wr + m * 16 + hi16 * 4 + r;
                const int col = bn + wc + n * 16 + r15;
                const size_t idx = (size_t)row * ldc + col;
                float v = acc[m][n][r];
                if (GELU) v = gelu_tanh(h2f(gate[idx])) * v;
                if (F16_OUT) ((u16*)Cout)[idx] = f2h(v);
                else         ((float*)Cout)[idx] = v;
            }
}

// ---------------------------------------------------------------------------
// 256x256-tile fp16 GEMM (round-10 proven variant): BK=32, 512 threads
// (8 waves 2Mx4N), double-buffered 64KB LDS, prefetch next K-tile via
// global_load_lds BEFORE computing current, single __syncthreads per K-step,
// setprio around MFMA cluster. LDS row-pairs of 128B, chunk8 ^= rp&7 swizzle;
// staging pre-swizzles the global source so linear gload_lds dest matches.
// ---------------------------------------------------------------------------
template<bool F16_OUT, bool GELU>
__global__ __launch_bounds__(512) void gemm256(const u16* __restrict__ A,
                                               const u16* __restrict__ Bt,
                                               void* __restrict__ Cout,
                                               const u16* __restrict__ gate,
                                               int Mt, int K, int ldc) {
    __shared__ u16 As[2][256 * 32];
    __shared__ u16 Bs[2][256 * 32];
    const int nwg = gridDim.x;
    const int q8 = nwg >> 3;
    const int dd = blockIdx.x;
    const int wk = (dd & 7) * q8 + (dd >> 3);   // bijective XCD-contiguous
    const int bm = (wk % Mt) * 256;
    const int bn = (wk / Mt) * 256;
    const int tid = threadIdx.x;
    const int lane = tid & 63;
    const int wid = tid >> 6;
    const int wm = wid >> 2, wn = wid & 3;      // wave grid 2x4
    const int r15 = lane & 15, hi16 = lane >> 4;

    f32x4 acc[8][4];
#pragma unroll
    for (int mi = 0; mi < 8; ++mi)
#pragma unroll
        for (int ni = 0; ni < 4; ++ni) acc[mi][ni] = (f32x4){0.f, 0.f, 0.f, 0.f};

    // staging pre-swizzle: lane slot (rp_local = lane>>3, slot = lane&7) holds
    // data chunk8 = slot ^ rp_local -> source row/kchunk derived from it.
    const int rpl  = lane >> 3;
    const int ch8d = (lane & 7) ^ rpl;
    const int sr   = wid * 16 + rpl * 2 + (ch8d >> 2);   // + i*128 (+ bm/bn)
    const int sk   = (ch8d & 3) * 8;                     // k offset within 32
    const int ldst = wid * 512;                          // u16; + i*4096

    const int nt = K / 32;
    {   // prologue: stage tile 0 into buf 0
        ldsload16(&A [(size_t)(bm + sr)       * K + sk], &As[0][ldst]);
        ldsload16(&A [(size_t)(bm + 128 + sr) * K + sk], &As[0][4096 + ldst]);
        ldsload16(&Bt[(size_t)(bn + sr)       * K + sk], &Bs[0][ldst]);
        ldsload16(&Bt[(size_t)(bn + 128 + sr) * K + sk], &Bs[0][4096 + ldst]);
    }
    __syncthreads();

    for (int t = 0; t < nt; ++t) {
        const int cur = t & 1;
        if (t + 1 < nt) {   // prefetch next tile into other buffer (overlaps compute)
            const int nb = cur ^ 1;
            const size_t k0 = (size_t)(t + 1) * 32 + sk;
            ldsload16(&A [(size_t)(bm + sr)       * K + k0], &As[nb][ldst]);
            ldsload16(&A [(size_t)(bm + 128 + sr) * K + k0], &As[nb][4096 + ldst]);
            ldsload16(&Bt[(size_t)(bn + sr)       * K + k0], &Bs[nb][ldst]);
            ldsload16(&Bt[(size_t)(bn + 128 + sr) * K + k0], &Bs[nb][4096 + ldst]);
        }
        const u16* Ab = As[cur];
        const u16* Bb = Bs[cur];
        f16x8 bf[4], af[8];
#pragma unroll
        for (int ni = 0; ni < 4; ++ni) {
            const int row = wn * 64 + ni * 16 + r15;
            const int rp = row >> 1;
            const int slot = (((row & 1) << 2) | hi16) ^ (rp & 7);
            bf[ni] = *(const f16x8*)&Bb[rp * 64 + slot * 8];
        }
#pragma unroll
        for (int mi = 0; mi < 8; ++mi) {
            const int row = wm * 128 + mi * 16 + r15;
            const int rp = row >> 1;
            const int slot = (((row & 1) << 2) | hi16) ^ (rp & 7);
            af[mi] = *(const f16x8*)&Ab[rp * 64 + slot * 8];
        }
        __builtin_amdgcn_s_setprio(1);
#pragma unroll
        for (int mi = 0; mi < 8; ++mi)
#pragma unroll
            for (int ni = 0; ni < 4; ++ni)
                acc[mi][ni] = __builtin_amdgcn_mfma_f32_16x16x32_f16(af[mi], bf[ni], acc[mi][ni], 0, 0, 0);
        __builtin_amdgcn_s_setprio(0);
        __syncthreads();   // drains vmcnt (prefetch landed) + all reads consumed
    }

#pragma unroll
    for (int mi = 0; mi < 8; ++mi)
#pragma unroll
        for (int ni = 0; ni < 4; ++ni)
#pragma unroll
            for (int r = 0; r < 4; ++r) {
                const int row = bm + wm * 128 + mi * 16 + hi16 * 4 + r;
                const int col = bn + wn * 64 + ni * 16 + r15;
                const size_t idx = (size_t)row * ldc + col;
                float v = acc[mi][ni][r];
                if (GELU) v = gelu_tanh(h2f(gate[idx])) * v;
                if (F16_OUT) ((u16*)Cout)[idx] = f2h(v);
                else         ((float*)Cout)[idx] = v;
            }
}

// ---------------------------------------------------------------------------
// batched QK^T scores (fp16): Sc[bh][q][k] fp32.  BK=64, swzK, tile skip.
// ---------------------------------------------------------------------------
__global__ __launch_bounds__(256) void qk_f16(const u16* __restrict__ Qh,
                                              const u16* __restrict__ Kh,
                                              float* __restrict__ Sc,
                                              int HDIM, int KVH, int win) {
    const int bm = blockIdx.y * 128;   // q tile
    const int bn = blockIdx.x * 128;   // k tile
    if (bn > bm + 127) return;
    if (win > 0 && bm - bn > win + 126) return;
    const int bh = blockIdx.z;
    const int b = bh / cH, h = bh % cH;
    const int kh = h / (cH / KVH);

    __shared__ u16 As[128 * 64];
    __shared__ u16 Bs[128 * 64];
    const int tid = threadIdx.x;
    const int lane = tid & 63;
    const int w = tid >> 6;
    const int wr = (w >> 1) * 64, wc = (w & 1) * 64;
    const int r15 = lane & 15, hi16 = lane >> 4;

    const int lda = cH * HDIM, ldb = KVH * HDIM;
    const u16* Aq = Qh + ((size_t)b * cS * cH + h) * HDIM;
    const u16* Bk = Kh + ((size_t)b * cS * KVH + kh) * HDIM;

    f32x4 acc[4][4];
#pragma unroll
    for (int m = 0; m < 4; ++m)
#pragma unroll
        for (int n = 0; n < 4; ++n) acc[m][n] = (f32x4){0.f, 0.f, 0.f, 0.f};

    int rA[4], cA[4], wl[4];
#pragma unroll
    for (int j = 0; j < 4; ++j) {
        const int c = tid + j * 256;
        rA[j] = c >> 3; cA[j] = (c & 7) * 8;
        wl[j] = swzK(rA[j], c & 7);
    }

    for (int k0 = 0; k0 < HDIM; k0 += 64) {
        uint4 av[4], bv[4];
#pragma unroll
        for (int j = 0; j < 4; ++j) {
            av[j] = *(const uint4*)&Aq[(size_t)(bm + rA[j]) * lda + k0 + cA[j]];
            bv[j] = *(const uint4*)&Bk[(size_t)(bn + rA[j]) * ldb + k0 + cA[j]];
        }
        __syncthreads();
#pragma unroll
        for (int j = 0; j < 4; ++j) {
            *(uint4*)&As[wl[j]] = av[j];
            *(uint4*)&Bs[wl[j]] = bv[j];
        }
        __syncthreads();
#pragma unroll
        for (int kk = 0; kk < 2; ++kk) {
            f16x8 af[4], bf4[4];
#pragma unroll
            for (int m = 0; m < 4; ++m)
                af[m] = *(const f16x8*)&As[swzK(wr + m * 16 + r15, kk * 4 + hi16)];
#pragma unroll
            for (int n = 0; n < 4; ++n)
                bf4[n] = *(const f16x8*)&Bs[swzK(wc + n * 16 + r15, kk * 4 + hi16)];
#pragma unroll
            for (int m = 0; m < 4; ++m)
#pragma unroll
                for (int n = 0; n < 4; ++n)
                    acc[m][n] = __builtin_amdgcn_mfma_f32_16x16x32_f16(af[m], bf4[n], acc[m][n], 0, 0, 0);
        }
    }
    float* Crow = Sc + (size_t)bh * cS * cS;
#pragma unroll
    for (int m = 0; m < 4; ++m)
#pragma unroll
        for (int n = 0; n < 4; ++n)
#pragma unroll
            for (int r = 0; r < 4; ++r)
                Crow[(size_t)(bm + wr + m * 16 + hi16 * 4 + r) * cS + bn + wc + n * 16 + r15]
                    = acc[m][n][r];
}

// ---------------------------------------------------------------------------
// row softmax over fp32 scores, in-place rewrite as fp16 P (row prefix).
// ---------------------------------------------------------------------------
__global__ __launch_bounds__(256) void softmax_kernel(float* __restrict__ Sc,
                                                      const int* __restrict__ tlen,
                                                      int win) {
    const int q = blockIdx.x, bh = blockIdx.y, b = bh / cH;
    float* row = Sc + ((size_t)bh * cS + q) * cS;
    u16* rowh = (u16*)row;
    const int tid = threadIdx.x;
    const int tl = tlen[b];
    const int kmax = min(q, tl - 1);
    const int kmin = (win > 0) ? max(0, q - win + 1) : 0;

    float v[4];
    float m = -1e30f;
#pragma unroll
    for (int j = 0; j < 4; ++j) {
        const int k = tid + j * 256;
        const bool ok = (k >= kmin && k <= kmax);
        v[j] = ok ? row[k] : -1e30f;
        m = fmaxf(m, v[j]);
    }
    for (int o = 32; o >= 1; o >>= 1) m = fmaxf(m, __shfl_xor(m, o));
    __shared__ float rb[8];
    if ((tid & 63) == 0) rb[tid >> 6] = m;
    __syncthreads();
    m = fmaxf(fmaxf(rb[0], rb[1]), fmaxf(rb[2], rb[3]));

    float e[4];
    float s = 0.f;
#pragma unroll
    for (int j = 0; j < 4; ++j) {
        const int k = tid + j * 256;
        const bool ok = (k >= kmin && k <= kmax);
        e[j] = ok ? expf(v[j] - m) : 0.f;
        s += e[j];
    }
    for (int o = 32; o >= 1; o >>= 1) s += __shfl_xor(s, o);
    __shared__ float sb[4];
    if ((tid & 63) == 0) sb[tid >> 6] = s;
    __syncthreads();
    s = sb[0] + sb[1] + sb[2] + sb[3];
    const float inv = 1.f / s;
    __syncthreads();   // fp32 reads complete before u16 overwrite
#pragma unroll
    for (int j = 0; j < 4; ++j) {
        const int k = tid + j * 256;
        rowh[k] = f2h(e[j] * inv);
    }
}

// ---------------------------------------------------------------------------
// batched PV (fp16): O[b,q,h*HDIM+d] = P[bh] @ Vt[b,kh]. BK=64, swzK.
// ---------------------------------------------------------------------------
__global__ __launch_bounds__(256) void pv_f16(const u16* __restrict__ P,
                                              const u16* __restrict__ Vt,
                                              u16* __restrict__ O,
                                              int HDIM, int KVH, int win) {
    const int bh = blockIdx.z;
    const int b = bh / cH, h = bh % cH;
    const int kh = h / (cH / KVH);
    const int bm = blockIdx.y * 128;   // q tile
    const int bn = blockIdx.x * 128;   // d tile

    __shared__ u16 As[128 * 64];
    __shared__ u16 Bs[128 * 64];
    const int tid = threadIdx.x;
    const int lane = tid & 63;
    const int w = tid >> 6;
    const int wr = (w >> 1) * 64, wc = (w & 1) * 64;
    const int r15 = lane & 15, hi16 = lane >> 4;

    const u16* Ap = P + (size_t)bh * cS * 2048;
    const u16* Bv = Vt + ((size_t)b * KVH + kh) * HDIM * cS;

    f32x4 acc[4][4];
#pragma unroll
    for (int m = 0; m < 4; ++m)
#pragma unroll
        for (int n = 0; n < 4; ++n) acc[m][n] = (f32x4){0.f, 0.f, 0.f, 0.f};

    int rA[4], cA[4], wl[4];
#pragma unroll
    for (int j = 0; j < 4; ++j) {
        const int c = tid + j * 256;
        rA[j] = c >> 3; cA[j] = (c & 7) * 8;
        wl[j] = swzK(rA[j], c & 7);
    }

    const int klo = (win > 0) ? (max(0, bm - win + 1) & ~63) : 0;
    const int khi = min(bm + 128, cS);

    for (int k0 = klo; k0 < khi; k0 += 64) {
        uint4 av[4], bv[4];
#pragma unroll
        for (int j = 0; j < 4; ++j) {
            av[j] = *(const uint4*)&Ap[(size_t)(bm + rA[j]) * 2048 + k0 + cA[j]];
            bv[j] = *(const uint4*)&Bv[(size_t)(bn + rA[j]) * cS + k0 + cA[j]];
        }
        __syncthreads();
#pragma unroll
        for (int j = 0; j < 4; ++j) {
            *(uint4*)&As[wl[j]] = av[j];
            *(uint4*)&Bs[wl[j]] = bv[j];
        }
        __syncthreads();
#pragma unroll
        for (int kk = 0; kk < 2; ++kk) {
            f16x8 af[4], bf4[4];
#pragma unroll
            for (int m = 0; m < 4; ++m)
                af[m] = *(const f16x8*)&As[swzK(wr + m * 16 + r15, kk * 4 + hi16)];
#pragma unroll
            for (int n = 0; n < 4; ++n)
                bf4[n] = *(const f16x8*)&Bs[swzK(wc + n * 16 + r15, kk * 4 + hi16)];
#pragma unroll
            for (int m = 0; m < 4; ++m)
#pragma unroll
                for (int n = 0; n < 4; ++n)
                    acc[m][n] = __builtin_amdgcn_mfma_f32_16x16x32_f16(af[m], bf4[n], acc[m][n], 0, 0, 0);
        }
    }
    const int ldo = cH * HDIM;
#pragma unroll
    for (int m = 0; m < 4; ++m)
#pragma unroll
        for (int n = 0; n < 4; ++n)
#pragma unroll
            for (int r = 0; r < 4; ++r) {
                const int q = bm + wr + m * 16 + hi16 * 4 + r;
                const int d = bn + wc + n * 16 + r15;
                O[(size_t)(b * cS + q) * ldo + h * HDIM + d] = f2h(acc[m][n][r]);
            }
}

// ---------------------------------------------------------------------------
extern "C" void kernel_launch(void* const* d_in, const int* in_sizes, int n_in,
                              void* d_out, int out_size, void* d_ws, size_t ws_size,
                              hipStream_t stream) {
    (void)in_sizes; (void)n_in; (void)out_size; (void)ws_size;
    const int*   tokens = (const int*)  d_in[0];
    const int*   tlen   = (const int*)  d_in[1];
    const float* embed  = (const float*)d_in[2];
    const float* norm_w = (const float*)d_in[3];
    const float* s_wq   = (const float*)d_in[4];
    const float* s_wk   = (const float*)d_in[5];
    const float* s_wv   = (const float*)d_in[6];
    const float* s_wo   = (const float*)d_in[7];
    const float* s_qn   = (const float*)d_in[8];
    const float* s_kn   = (const float*)d_in[9];
    const float* s_wg   = (const float*)d_in[10];
    const float* s_wu   = (const float*)d_in[11];
    const float* s_wd   = (const float*)d_in[12];
    const float* s_ln1  = (const float*)d_in[13];
    const float* s_ln2  = (const float*)d_in[14];
    const float* s_ln3  = (const float*)d_in[15];
    const float* s_ln4  = (const float*)d_in[16];
    const float* s_scal = (const float*)d_in[17];
    const float* g_wq   = (const float*)d_in[18];
    const float* g_wk   = (const float*)d_in[19];
    const float* g_wo   = (const float*)d_in[20];
    const float* g_qn   = (const float*)d_in[21];
    const float* g_kn   = (const float*)d_in[22];
    const float* g_wg   = (const float*)d_in[23];
    const float* g_wu   = (const float*)d_in[24];
    const float* g_wd   = (const float*)d_in[25];
    const float* g_ln1  = (const float*)d_in[26];
    const float* g_ln2  = (const float*)d_in[27];
    const float* g_ln3  = (const float*)d_in[28];
    const float* g_ln4  = (const float*)d_in[29];
    const float* g_scal = (const float*)d_in[30];

    // workspace (peak <156 MiB), phase-disjoint (round-13 plan)
    char* w8 = (char*)d_ws;
    float* x   = (float*)(w8);
    u16*   ab  = (u16*)(w8 + 16 * MB);
    u16*   wp  = (u16*)(w8 + 24 * MB);
    u16*   Qb  = (u16*)(w8 + 24 * MB);
    u16*   Ob  = (u16*)(w8 + 24 * MB);
    u16*   embH= (u16*)(w8 + 24 * MB);
    u16*   t0b = (u16*)(w8 + 56 * MB);
    u16*   Kb  = (u16*)(w8 + 58 * MB);
    u16*   Vt  = (u16*)(w8 + 75 * MB);
    float* qkg = (float*)(w8 + 84 * MB);
    float* scores = (float*)(w8 + 84 * MB);
    u16*   Pb  = (u16*)(w8 + 84 * MB);
    u16*   wo2 = (u16*)(w8 + 84 * MB);
    u16*   t1b = (u16*)(w8 + 88 * MB);
    float* r0  = (float*)(w8 + 116 * MB);
    float* fo  = (float*)(w8 + 120 * MB);
    float* vf  = (float*)(w8 + 132 * MB);

    auto tcast = [&](const float* in, u16* outp, int K, int N, int ldin) {
        tcast_kernel<<<dim3(N / 32, K / 32), 256, 0, stream>>>(in, outp, K, N, ldin);
    };
    auto gemmF = [&](const u16* A, const u16* Bt, float* C, int N, int K, int ldc) {
        gemm_f16<false, false><<<16 * (N / 128), 256, 0, stream>>>(A, Bt, C, nullptr, 16, K, ldc);
    };
    auto g256H = [&](const u16* A, const u16* Bt, u16* C, int N, int K, int ldc) {
        gemm256<true, false><<<8 * (N / 256), 512, 0, stream>>>(A, Bt, C, nullptr, 8, K, ldc);
    };
    auto g256HG = [&](const u16* A, const u16* Bt, u16* C, const u16* gate,
                      int N, int K, int ldc) {
        gemm256<true, true><<<8 * (N / 256), 512, 0, stream>>>(A, Bt, C, gate, 8, K, ldc);
    };

    // attention core: Qb/Kb fp16 + vf fp32 (dense) ready; writes Ob fp16
    auto attention = [&](int HDIM, int KVH, int win) {
        vtrans_kernel<<<dim3(HDIM / 32, cS / 32, cB * KVH), 256, 0, stream>>>(vf, Vt, HDIM, KVH);
        qk_f16<<<dim3(cS / 128, cS / 128, cB * cH), 256, 0, stream>>>(
            Qb, Kb, scores, HDIM, KVH, win);
        softmax_kernel<<<dim3(cS, cB * cH), 256, 0, stream>>>(scores, tlen, win);
        pv_f16<<<dim3(HDIM / 128, cS / 128, cB * cH), 256, 0, stream>>>(
            Pb, Vt, Ob, HDIM, KVH, win);
    };

    embed_kernel<<<cM, 256, 0, stream>>>(tokens, embed, x);

    // ================= block 1: sliding-window =================
    rms_f16_kernel<<<cM, 256, 0, stream>>>(x, s_ln1, ab, cD);
    tcast(s_wq, wp, cD, cH * cHD, cH * cHD);
    tcast(s_wk, wp + (size_t)2048 * cD, cD, cKV * cHD, cKV * cHD);
    tcast(s_wv, wp + (size_t)3072 * cD, cD, cKV * cHD, cKV * cHD);
    gemmF(ab, wp, qkg, 4096, cD, 4096);                               // [M,4096] q|k|v
    rms_kernel<<<cM * cKV, 256, 0, stream>>>(qkg + 3072, nullptr, vf, cHD, 4096, cKV);
    rmsrope_kernel<<<cM * cH, 128, 0, stream>>>(qkg, s_qn, Qb, cH, cHD, cHD, 10000.f, 4096);
    rmsrope_kernel<<<cM * cKV, 128, 0, stream>>>(qkg + 2048, s_kn, Kb, cKV, cHD, cHD, 10000.f, 4096);
    attention(cHD, cKV, cWIN);
    tcast(s_wo, wo2, cH * cHD, cD, cD);
    gemmF(Ob, wo2, r0, cD, cH * cHD, cD);
    addnorm_kernel<<<cM, 256, 0, stream>>>(x, r0, s_ln2, nullptr, s_ln3, x, ab);
    tcast(s_wg, wp, cD, cF, cF);
    g256H(ab, wp, t1b, cF, cD, cF);                 // gate -> t1b
    tcast(s_wu, wp, cD, cF, cF);
    g256HG(ab, wp, t0b, t1b, cF, cD, cF);           // gelu(gate)*up -> t0b
    tcast(s_wd, wp, cF, cD, cD);
    gemmF(t0b, wp, fo, cD, cF, cD);
    addnorm_kernel<<<cM, 256, 0, stream>>>(x, fo, s_ln4, s_scal, g_ln1, x, ab);

    // ================= block 2: global =================
    tcast(g_wq, wp, cD, cH * cGHD, cH * cGHD);
    tcast(g_wk, wp + (size_t)4096 * cD, cD, cGKV * cGHD, cGKV * cGHD);
    gemmF(ab, wp, qkg, 6144, cD, 6144);                               // [M,6144] q|k
    rms_kernel<<<cM * cGKV, 256, 0, stream>>>(qkg + 4096, nullptr, vf, cGHD, 6144, cGKV);
    rmsrope_kernel<<<cM * cH, 128, 0, stream>>>(qkg, g_qn, Qb, cH, cGHD, cROT, 1000000.f, 6144);
    rmsrope_kernel<<<cM * cGKV, 128, 0, stream>>>(qkg + 4096, g_kn, Kb, cGKV, cGHD, cROT, 1000000.f, 6144);
    attention(cGHD, cGKV, 0);
    tcast(g_wo, wo2, cH * cGHD, cD, cD);
    gemmF(Ob, wo2, r0, cD, cH * cGHD, cD);
    addnorm_kernel<<<cM, 256, 0, stream>>>(x, r0, g_ln2, nullptr, g_ln3, x, ab);
    tcast(g_wg, wp, cD, cF, cF);
    g256H(ab, wp, t1b, cF, cD, cF);
    tcast(g_wu, wp, cD, cF, cF);
    g256HG(ab, wp, t0b, t1b, cF, cD, cF);
    tcast(g_wd, wp, cF, cD, cD);
    gemmF(t0b, wp, fo, cD, cF, cD);
    addnorm_kernel<<<cM, 256, 0, stream>>>(x, fo, g_ln4, g_scal, norm_w, x, ab);

    // ================= logits: cast embed to fp16, 256^2 GEMM ==========
    cast_f16_kernel<<<(cV * cD / 4 + 255) / 256, 256, 0, stream>>>(embed, embH, cV * cD);
    gemm256<false, false><<<8 * (cV / 256), 512, 0, stream>>>(
        ab, embH, (float*)d_out, nullptr, 8, cD, cV);
}

// Round 16
// 1923.774 us; speedup vs baseline: 1.0653x; 1.0097x over previous
//
#include <hip/hip_runtime.h>
#include <math.h>

typedef unsigned short u16;
typedef _Float16 f16;
typedef __attribute__((ext_vector_type(8))) _Float16 f16x8;
typedef __attribute__((ext_vector_type(4))) float f32x4;

// ---- problem constants ----
constexpr int cB   = 2;
constexpr int cS   = 1024;
constexpr int cD   = 2048;
constexpr int cH   = 8;
constexpr int cHD  = 256;
constexpr int cKV  = 4;
constexpr int cGHD = 512;
constexpr int cGKV = 4;
constexpr int cROT = 128;
constexpr int cF   = 8192;
constexpr int cV   = 32000;
constexpr int cWIN = 512;
constexpr int cM   = cB * cS;   // 2048 token rows
constexpr float cEPS = 1e-6f;
constexpr size_t MB = 1024 * 1024;

__device__ inline u16 f2h(float x) { union { f16 h; u16 u; } c; c.h = (f16)x; return c.u; }
__device__ inline float h2f(u16 v) { union { u16 u; f16 h; } c; c.u = v; return (float)c.h; }

// swizzled LDS u16-index: [128][32] u16 rows, 16B chunks XOR'd by (row>>1)&3.
__device__ inline int swz16(int row, int chunk) {
    return row * 32 + ((chunk ^ ((row >> 1) & 3)) << 3);
}
// swizzle for BK=64 fp16 arrays (qk/pv): [row][64] u16, 16B chunk ^= row&7
__device__ inline int swzK(int row, int ch) {
    return row * 64 + ((ch ^ (row & 7)) << 3);
}

// async 16B global->LDS (wave-uniform LDS base + lane*16; per-lane global addr)
typedef __attribute__((address_space(1))) const unsigned int gu32;
typedef __attribute__((address_space(3))) unsigned int lu32;
__device__ inline void ldsload16(const u16* g, u16* l) {
    __builtin_amdgcn_global_load_lds((gu32*)g, (lu32*)l, 16, 0, 0);
}

__device__ inline float gelu_tanh(float v) {
    const float t = tanhf(0.7978845608028654f * (v + 0.044715f * v * v * v));
    return 0.5f * v * (1.f + t);
}

// ---------------------------------------------------------------------------
// embed lookup * sqrt(D)
// ---------------------------------------------------------------------------
__global__ void embed_kernel(const int* __restrict__ tok,
                             const float* __restrict__ emb,
                             float* __restrict__ out) {
    const int row = blockIdx.x;
    const int t = tok[row];
    const float* e = emb + (size_t)t * cD;
    float* o = out + (size_t)row * cD;
    const float sc = sqrtf((float)cD);
    for (int d = threadIdx.x; d < cD; d += blockDim.x) o[d] = e[d] * sc;
}

// ---------------------------------------------------------------------------
// row RMS norm fp32->fp32.  Input rows may live in a wider matrix:
// in offset = (row/nh)*xld + (row%nh)*dim ; output is dense (row*dim).
// ---------------------------------------------------------------------------
__global__ void rms_kernel(const float* __restrict__ x,
                           const float* __restrict__ w,
                           float* __restrict__ out, int dim, int xld, int nh) {
    const int row = blockIdx.x;
    const float* xr = x + (size_t)(row / nh) * xld + (size_t)(row % nh) * dim;
    float* orow = out + (size_t)row * dim;
    float ss = 0.f;
    for (int d = threadIdx.x; d < dim; d += blockDim.x) { float v = xr[d]; ss += v * v; }
    for (int o = 32; o >= 1; o >>= 1) ss += __shfl_xor(ss, o);
    __shared__ float rb[8];
    if ((threadIdx.x & 63) == 0) rb[threadIdx.x >> 6] = ss;
    __syncthreads();
    ss = rb[0] + rb[1] + rb[2] + rb[3];
    const float r = rsqrtf(ss / dim + cEPS);
    for (int d = threadIdx.x; d < dim; d += blockDim.x)
        orow[d] = xr[d] * r * (w ? w[d] : 1.f);
}

// row RMS norm fp32 -> fp16 (dense both sides)
__global__ void rms_f16_kernel(const float* __restrict__ x,
                               const float* __restrict__ w,
                               u16* __restrict__ out, int dim) {
    const int row = blockIdx.x;
    const float* xr = x + (size_t)row * dim;
    u16* orow = out + (size_t)row * dim;
    float ss = 0.f;
    for (int d = threadIdx.x; d < dim; d += blockDim.x) { float v = xr[d]; ss += v * v; }
    for (int o = 32; o >= 1; o >>= 1) ss += __shfl_xor(ss, o);
    __shared__ float rb[8];
    if ((threadIdx.x & 63) == 0) rb[threadIdx.x >> 6] = ss;
    __syncthreads();
    ss = rb[0] + rb[1] + rb[2] + rb[3];
    const float r = rsqrtf(ss / dim + cEPS);
    for (int d = threadIdx.x; d < dim; d += blockDim.x)
        orow[d] = f2h(xr[d] * r * (w ? w[d] : 1.f));
}

// ---------------------------------------------------------------------------
// fused: x_new = (res + y*rms(y)*w_add) * scal ; ab = fp16(x_new*rms(x_new)*w_norm)
// ---------------------------------------------------------------------------
__global__ __launch_bounds__(256) void addnorm_kernel(const float* __restrict__ res,
                                                      const float* __restrict__ y,
                                                      const float* __restrict__ w_add,
                                                      const float* __restrict__ scal,
                                                      const float* __restrict__ w_norm,
                                                      float* __restrict__ xout,
                                                      u16* __restrict__ abo) {
    const int row = blockIdx.x;
    const float* yr = y + (size_t)row * cD;
    const float* rr = res + (size_t)row * cD;
    float* xo = xout + (size_t)row * cD;
    u16* ao = abo + (size_t)row * cD;
    const int tid = threadIdx.x;
    __shared__ float rb[4];

    float yl[8], xl[8];
    float ss = 0.f;
#pragma unroll
    for (int j = 0; j < 8; ++j) { yl[j] = yr[tid + j * 256]; ss += yl[j] * yl[j]; }
    for (int o = 32; o >= 1; o >>= 1) ss += __shfl_xor(ss, o);
    if ((tid & 63) == 0) rb[tid >> 6] = ss;
    __syncthreads();
    ss = rb[0] + rb[1] + rb[2] + rb[3];
    const float r1 = rsqrtf(ss / cD + cEPS);
    const float sc = scal ? *scal : 1.f;

    float ss2 = 0.f;
#pragma unroll
    for (int j = 0; j < 8; ++j) {
        const int d = tid + j * 256;
        xl[j] = (rr[d] + yl[j] * r1 * w_add[d]) * sc;
        ss2 += xl[j] * xl[j];
    }
    for (int o = 32; o >= 1; o >>= 1) ss2 += __shfl_xor(ss2, o);
    __syncthreads();
    if ((tid & 63) == 0) rb[tid >> 6] = ss2;
    __syncthreads();
    ss2 = rb[0] + rb[1] + rb[2] + rb[3];
    const float r2 = rsqrtf(ss2 / cD + cEPS);
#pragma unroll
    for (int j = 0; j < 8; ++j) {
        const int d = tid + j * 256;
        xo[d] = xl[j];
        ao[d] = f2h(xl[j] * r2 * w_norm[d]);
    }
}

// ---------------------------------------------------------------------------
// fused: rms(x)*w -> partial rope -> fp16.  one block (128 thr) per head-row.
// input offset = (row/NH)*xld + (row%NH)*HDIM ; out dense row*HDIM.
// powf replaced by single exp2f with hoisted log2(theta) (2 fewer
// transcendentals per pair; angle error <=1e-4 rad, below fp16 rounding).
// ---------------------------------------------------------------------------
__global__ __launch_bounds__(128) void rmsrope_kernel(const float* __restrict__ x,
                                                      const float* __restrict__ w,
                                                      u16* __restrict__ out,
                                                      int NH, int HDIM, int rot,
                                                      float theta, int xld) {
    const int row = blockIdx.x;
    const int s = (row / NH) % cS;
    const float* xr = x + (size_t)(row / NH) * xld + (size_t)(row % NH) * HDIM;
    u16* orow = out + (size_t)row * HDIM;
    const int tid = threadIdx.x;
    const int np = HDIM >> 1;
    const float nl2t = -__log2f(theta) * (2.f / (float)rot);   // exp2 scale
    __shared__ float rb[2];

    float v1[2], v2[2];
    float ss = 0.f;
    for (int p = tid, j = 0; p < np; p += 128, ++j) {
        v1[j] = xr[2 * p]; v2[j] = xr[2 * p + 1];
        ss += v1[j] * v1[j] + v2[j] * v2[j];
    }
    for (int o = 32; o >= 1; o >>= 1) ss += __shfl_xor(ss, o);
    if ((tid & 63) == 0) rb[tid >> 6] = ss;
    __syncthreads();
    ss = rb[0] + rb[1];
    const float r = rsqrtf(ss / HDIM + cEPS);
    const int halfrot = rot >> 1;
    for (int p = tid, j = 0; p < np; p += 128, ++j) {
        const float a = v1[j] * r * w[2 * p];
        const float b = v2[j] * r * w[2 * p + 1];
        float o1 = a, o2 = b;
        if (p < halfrot) {
            const float inv = exp2f((float)p * nl2t);   // theta^(-2p/rot)
            const float ang = (float)s * inv;
            const float c = cosf(ang), sn = sinf(ang);
            o1 = a * c - b * sn;
            o2 = a * sn + b * c;
        }
        orow[2 * p]     = f2h(o1);
        orow[2 * p + 1] = f2h(o2);
    }
}

// ---------------------------------------------------------------------------
// fp32 [K][N] (row stride ldin) -> fp16 [N][K]
// ---------------------------------------------------------------------------
__global__ __launch_bounds__(256) void tcast_kernel(const float* __restrict__ in,
                                                    u16* __restrict__ out,
                                                    int K, int N, int ldin) {
    __shared__ float t[32][33];
    const int kt = blockIdx.y * 32, nt = blockIdx.x * 32;
    const int tx = threadIdx.x & 31, ty = threadIdx.x >> 5;   // ty 0..7
#pragma unroll
    for (int j = 0; j < 4; ++j)
        t[ty + j * 8][tx] = in[(size_t)(kt + ty + j * 8) * ldin + nt + tx];
    __syncthreads();
#pragma unroll
    for (int j = 0; j < 4; ++j)
        out[(size_t)(nt + ty + j * 8) * K + kt + tx] = f2h(t[tx][ty + j * 8]);
}

// fp32 -> fp16 elementwise (4 per thread)
__global__ void cast_f16_kernel(const float* __restrict__ in, u16* __restrict__ out,
                                int n) {
    const int i = blockIdx.x * blockDim.x + threadIdx.x;
    if (i * 4 >= n) return;
    const float4 v = *(const float4*)&in[(size_t)i * 4];
    uint2 o;
    o.x = (unsigned)f2h(v.x) | ((unsigned)f2h(v.y) << 16);
    o.y = (unsigned)f2h(v.z) | ((unsigned)f2h(v.w) << 16);
    *(uint2*)&out[(size_t)i * 4] = o;
}

// V fp32 [B,S,KVH,HDIM] dense -> Vt fp16 [B*KVH, HDIM, S]
__global__ __launch_bounds__(256) void vtrans_kernel(const float* __restrict__ V,
                                                     u16* __restrict__ Vt,
                                                     int HDIM, int KVH) {
    __shared__ float t[32][33];
    const int bk = blockIdx.z;
    const int b = bk / KVH, kh = bk % KVH;
    const int st = blockIdx.y * 32, dt = blockIdx.x * 32;
    const int tx = threadIdx.x & 31, ty = threadIdx.x >> 5;
#pragma unroll
    for (int j = 0; j < 4; ++j)
        t[ty + j * 8][tx] = V[((size_t)(b * cS + st + ty + j * 8) * KVH + kh) * HDIM + dt + tx];
    __syncthreads();
#pragma unroll
    for (int j = 0; j < 4; ++j)
        Vt[((size_t)bk * HDIM + dt + ty + j * 8) * cS + st + tx] = f2h(t[tx][ty + j * 8]);
}

// ---------------------------------------------------------------------------
// fp16 MFMA GEMM (m97 structure, 128x128, BK=32): for small-N GEMMs.
// ---------------------------------------------------------------------------
template<bool F16_OUT, bool GELU>
__global__ __launch_bounds__(256) void gemm_f16(const u16* __restrict__ A,
                                                const u16* __restrict__ Bt,
                                                void* __restrict__ Cout,
                                                const u16* __restrict__ gate,
                                                int Mt, int K, int ldc) {
    __shared__ u16 As[128 * 32];
    __shared__ u16 Bs[128 * 32];
    const int nwg = gridDim.x;
    const int q8 = nwg >> 3;
    const int dd = blockIdx.x;
    const int wk = (dd & 7) * q8 + (dd >> 3);       // bijective XCD-contiguous
    const int bm = (wk % Mt) * 128;
    const int bn = (wk / Mt) * 128;
    const int tid = threadIdx.x;
    const int lane = tid & 63;
    const int wv = tid >> 6;
    const int wr = (wv >> 1) * 64, wc = (wv & 1) * 64;
    const int r15 = lane & 15, hi16 = lane >> 4;

    f32x4 acc[4][4];
#pragma unroll
    for (int m = 0; m < 4; ++m)
#pragma unroll
        for (int n = 0; n < 4; ++n) acc[m][n] = (f32x4){0.f, 0.f, 0.f, 0.f};

    int rowS[2], koS[2];
#pragma unroll
    for (int i = 0; i < 2; ++i) {
        const int s = i * 256 + tid;
        rowS[i] = s >> 2;
        koS[i] = ((s & 3) ^ ((rowS[i] >> 1) & 3)) * 8;
    }
    u16* ldsA0 = &As[(wv * 64) * 8];
    u16* ldsA1 = &As[(256 + wv * 64) * 8];
    u16* ldsB0 = &Bs[(wv * 64) * 8];
    u16* ldsB1 = &Bs[(256 + wv * 64) * 8];

    for (int k0 = 0; k0 < K; k0 += 32) {
        __syncthreads();
        ldsload16(&A [(size_t)(bm + rowS[0]) * K + k0 + koS[0]], ldsA0);
        ldsload16(&A [(size_t)(bm + rowS[1]) * K + k0 + koS[1]], ldsA1);
        ldsload16(&Bt[(size_t)(bn + rowS[0]) * K + k0 + koS[0]], ldsB0);
        ldsload16(&Bt[(size_t)(bn + rowS[1]) * K + k0 + koS[1]], ldsB1);
        __syncthreads();
        f16x8 af[4], bf4[4];
#pragma unroll
        for (int m = 0; m < 4; ++m)
            af[m] = *(const f16x8*)&As[swz16(wr + m * 16 + r15, hi16)];
#pragma unroll
        for (int n = 0; n < 4; ++n)
            bf4[n] = *(const f16x8*)&Bs[swz16(wc + n * 16 + r15, hi16)];
#pragma unroll
        for (int m = 0; m < 4; ++m)
#pragma unroll
            for (int n = 0; n < 4; ++n)
                acc[m][n] = __builtin_amdgcn_mfma_f32_16x16x32_f16(af[m], bf4[n], acc[m][n], 0, 0, 0);
    }
#pragma unroll
    for (int m = 0; m < 4; ++m)
#pragma unroll
        for (int n = 0; n < 4; ++n)
#pragma unroll
            for (int r = 0; r < 4; ++r) {
                const int row = bm + wr + m * 16 + hi16 * 4 + r;
                const int col = bn + wc + n * 16 + r15;
                const size_t idx = (size_t)row * ldc + col;
                float v = acc[m][n][r];
                if (GELU) v = gelu_tanh(h2f(gate[idx])) * v;
                if (F16_OUT) ((u16*)Cout)[idx] = f2h(v);
                else         ((float*)Cout)[idx] = v;
            }
}

// ---------------------------------------------------------------------------
// 256x256-tile fp16 GEMM (round-10 proven variant): BK=32, 512 threads
// (8 waves 2Mx4N), double-buffered 64KB LDS, prefetch next K-tile via
// global_load_lds BEFORE computing current, single __syncthreads per K-step,
// setprio around MFMA cluster. LDS row-pairs of 128B, chunk8 ^= rp&7 swizzle;
// staging pre-swizzles the global source so linear gload_lds dest matches.
// ---------------------------------------------------------------------------
template<bool F16_OUT, bool GELU>
__global__ __launch_bounds__(512) void gemm256(const u16* __restrict__ A,
                                               const u16* __restrict__ Bt,
                                               void* __restrict__ Cout,
                                               const u16* __restrict__ gate,
                                               int Mt, int K, int ldc) {
    __shared__ u16 As[2][256 * 32];
    __shared__ u16 Bs[2][256 * 32];
    const int nwg = gridDim.x;
    const int q8 = nwg >> 3;
    const int dd = blockIdx.x;
    const int wk = (dd & 7) * q8 + (dd >> 3);   // bijective XCD-contiguous
    const int bm = (wk % Mt) * 256;
    const int bn = (wk / Mt) * 256;
    const int tid = threadIdx.x;
    const int lane = tid & 63;
    const int wid = tid >> 6;
    const int wm = wid >> 2, wn = wid & 3;      // wave grid 2x4
    const int r15 = lane & 15, hi16 = lane >> 4;

    f32x4 acc[8][4];
#pragma unroll
    for (int mi = 0; mi < 8; ++mi)
#pragma unroll
        for (int ni = 0; ni < 4; ++ni) acc[mi][ni] = (f32x4){0.f, 0.f, 0.f, 0.f};

    // staging pre-swizzle: lane slot (rp_local = lane>>3, slot = lane&7) holds
    // data chunk8 = slot ^ rp_local -> source row/kchunk derived from it.
    const int rpl  = lane >> 3;
    const int ch8d = (lane & 7) ^ rpl;
    const int sr   = wid * 16 + rpl * 2 + (ch8d >> 2);   // + i*128 (+ bm/bn)
    const int sk   = (ch8d & 3) * 8;                     // k offset within 32
    const int ldst = wid * 512;                          // u16; + i*4096

    const int nt = K / 32;
    {   // prologue: stage tile 0 into buf 0
        ldsload16(&A [(size_t)(bm + sr)       * K + sk], &As[0][ldst]);
        ldsload16(&A [(size_t)(bm + 128 + sr) * K + sk], &As[0][4096 + ldst]);
        ldsload16(&Bt[(size_t)(bn + sr)       * K + sk], &Bs[0][ldst]);
        ldsload16(&Bt[(size_t)(bn + 128 + sr) * K + sk], &Bs[0][4096 + ldst]);
    }
    __syncthreads();

    for (int t = 0; t < nt; ++t) {
        const int cur = t & 1;
        if (t + 1 < nt) {   // prefetch next tile into other buffer (overlaps compute)
            const int nb = cur ^ 1;
            const size_t k0 = (size_t)(t + 1) * 32 + sk;
            ldsload16(&A [(size_t)(bm + sr)       * K + k0], &As[nb][ldst]);
            ldsload16(&A [(size_t)(bm + 128 + sr) * K + k0], &As[nb][4096 + ldst]);
            ldsload16(&Bt[(size_t)(bn + sr)       * K + k0], &Bs[nb][ldst]);
            ldsload16(&Bt[(size_t)(bn + 128 + sr) * K + k0], &Bs[nb][4096 + ldst]);
        }
        const u16* Ab = As[cur];
        const u16* Bb = Bs[cur];
        f16x8 bf[4], af[8];
#pragma unroll
        for (int ni = 0; ni < 4; ++ni) {
            const int row = wn * 64 + ni * 16 + r15;
            const int rp = row >> 1;
            const int slot = (((row & 1) << 2) | hi16) ^ (rp & 7);
            bf[ni] = *(const f16x8*)&Bb[rp * 64 + slot * 8];
        }
#pragma unroll
        for (int mi = 0; mi < 8; ++mi) {
            const int row = wm * 128 + mi * 16 + r15;
            const int rp = row >> 1;
            const int slot = (((row & 1) << 2) | hi16) ^ (rp & 7);
            af[mi] = *(const f16x8*)&Ab[rp * 64 + slot * 8];
        }
        __builtin_amdgcn_s_setprio(1);
#pragma unroll
        for (int mi = 0; mi < 8; ++mi)
#pragma unroll
            for (int ni = 0; ni < 4; ++ni)
                acc[mi][ni] = __builtin_amdgcn_mfma_f32_16x16x32_f16(af[mi], bf[ni], acc[mi][ni], 0, 0, 0);
        __builtin_amdgcn_s_setprio(0);
        __syncthreads();   // drains vmcnt (prefetch landed) + all reads consumed
    }

#pragma unroll
    for (int mi = 0; mi < 8; ++mi)
#pragma unroll
        for (int ni = 0; ni < 4; ++ni)
#pragma unroll
            for (int r = 0; r < 4; ++r) {
                const int row = bm + wm * 128 + mi * 16 + hi16 * 4 + r;
                const int col = bn + wn * 64 + ni * 16 + r15;
                const size_t idx = (size_t)row * ldc + col;
                float v = acc[mi][ni][r];
                if (GELU) v = gelu_tanh(h2f(gate[idx])) * v;
                if (F16_OUT) ((u16*)Cout)[idx] = f2h(v);
                else         ((float*)Cout)[idx] = v;
            }
}

// ---------------------------------------------------------------------------
// batched QK^T scores (fp16): Sc[bh][q][k] fp32.  BK=64, swzK, tile skip.
// ---------------------------------------------------------------------------
__global__ __launch_bounds__(256) void qk_f16(const u16* __restrict__ Qh,
                                              const u16* __restrict__ Kh,
                                              float* __restrict__ Sc,
                                              int HDIM, int KVH, int win) {
    const int bm = blockIdx.y * 128;   // q tile
    const int bn = blockIdx.x * 128;   // k tile
    if (bn > bm + 127) return;
    if (win > 0 && bm - bn > win + 126) return;
    const int bh = blockIdx.z;
    const int b = bh / cH, h = bh % cH;
    const int kh = h / (cH / KVH);

    __shared__ u16 As[128 * 64];
    __shared__ u16 Bs[128 * 64];
    const int tid = threadIdx.x;
    const int lane = tid & 63;
    const int w = tid >> 6;
    const int wr = (w >> 1) * 64, wc = (w & 1) * 64;
    const int r15 = lane & 15, hi16 = lane >> 4;

    const int lda = cH * HDIM, ldb = KVH * HDIM;
    const u16* Aq = Qh + ((size_t)b * cS * cH + h) * HDIM;
    const u16* Bk = Kh + ((size_t)b * cS * KVH + kh) * HDIM;

    f32x4 acc[4][4];
#pragma unroll
    for (int m = 0; m < 4; ++m)
#pragma unroll
        for (int n = 0; n < 4; ++n) acc[m][n] = (f32x4){0.f, 0.f, 0.f, 0.f};

    int rA[4], cA[4], wl[4];
#pragma unroll
    for (int j = 0; j < 4; ++j) {
        const int c = tid + j * 256;
        rA[j] = c >> 3; cA[j] = (c & 7) * 8;
        wl[j] = swzK(rA[j], c & 7);
    }

    for (int k0 = 0; k0 < HDIM; k0 += 64) {
        uint4 av[4], bv[4];
#pragma unroll
        for (int j = 0; j < 4; ++j) {
            av[j] = *(const uint4*)&Aq[(size_t)(bm + rA[j]) * lda + k0 + cA[j]];
            bv[j] = *(const uint4*)&Bk[(size_t)(bn + rA[j]) * ldb + k0 + cA[j]];
        }
        __syncthreads();
#pragma unroll
        for (int j = 0; j < 4; ++j) {
            *(uint4*)&As[wl[j]] = av[j];
            *(uint4*)&Bs[wl[j]] = bv[j];
        }
        __syncthreads();
#pragma unroll
        for (int kk = 0; kk < 2; ++kk) {
            f16x8 af[4], bf4[4];
#pragma unroll
            for (int m = 0; m < 4; ++m)
                af[m] = *(const f16x8*)&As[swzK(wr + m * 16 + r15, kk * 4 + hi16)];
#pragma unroll
            for (int n = 0; n < 4; ++n)
                bf4[n] = *(const f16x8*)&Bs[swzK(wc + n * 16 + r15, kk * 4 + hi16)];
#pragma unroll
            for (int m = 0; m < 4; ++m)
#pragma unroll
                for (int n = 0; n < 4; ++n)
                    acc[m][n] = __builtin_amdgcn_mfma_f32_16x16x32_f16(af[m], bf4[n], acc[m][n], 0, 0, 0);
        }
    }
    float* Crow = Sc + (size_t)bh * cS * cS;
#pragma unroll
    for (int m = 0; m < 4; ++m)
#pragma unroll
        for (int n = 0; n < 4; ++n)
#pragma unroll
            for (int r = 0; r < 4; ++r)
                Crow[(size_t)(bm + wr + m * 16 + hi16 * 4 + r) * cS + bn + wc + n * 16 + r15]
                    = acc[m][n][r];
}

// ---------------------------------------------------------------------------
// row softmax over fp32 scores, in-place rewrite as fp16 P (row prefix).
// ---------------------------------------------------------------------------
__global__ __launch_bounds__(256) void softmax_kernel(float* __restrict__ Sc,
                                                      const int* __restrict__ tlen,
                                                      int win) {
    const int q = blockIdx.x, bh = blockIdx.y, b = bh / cH;
    float* row = Sc + ((size_t)bh * cS + q) * cS;
    u16* rowh = (u16*)row;
    const int tid = threadIdx.x;
    const int tl = tlen[b];
    const int kmax = min(q, tl - 1);
    const int kmin = (win > 0) ? max(0, q - win + 1) : 0;

    float v[4];
    float m = -1e30f;
#pragma unroll
    for (int j = 0; j < 4; ++j) {
        const int k = tid + j * 256;
        const bool ok = (k >= kmin && k <= kmax);
        v[j] = ok ? row[k] : -1e30f;
        m = fmaxf(m, v[j]);
    }
    for (int o = 32; o >= 1; o >>= 1) m = fmaxf(m, __shfl_xor(m, o));
    __shared__ float rb[8];
    if ((tid & 63) == 0) rb[tid >> 6] = m;
    __syncthreads();
    m = fmaxf(fmaxf(rb[0], rb[1]), fmaxf(rb[2], rb[3]));

    float e[4];
    float s = 0.f;
#pragma unroll
    for (int j = 0; j < 4; ++j) {
        const int k = tid + j * 256;
        const bool ok = (k >= kmin && k <= kmax);
        e[j] = ok ? expf(v[j] - m) : 0.f;
        s += e[j];
    }
    for (int o = 32; o >= 1; o >>= 1) s += __shfl_xor(s, o);
    __shared__ float sb[4];
    if ((tid & 63) == 0) sb[tid >> 6] = s;
    __syncthreads();
    s = sb[0] + sb[1] + sb[2] + sb[3];
    const float inv = 1.f / s;
    __syncthreads();   // fp32 reads complete before u16 overwrite
#pragma unroll
    for (int j = 0; j < 4; ++j) {
        const int k = tid + j * 256;
        rowh[k] = f2h(e[j] * inv);
    }
}

// ---------------------------------------------------------------------------
// batched PV (fp16): O[b,q,h*HDIM+d] = P[bh] @ Vt[b,kh]. BK=64, swzK.
// ---------------------------------------------------------------------------
__global__ __launch_bounds__(256) void pv_f16(const u16* __restrict__ P,
                                              const u16* __restrict__ Vt,
                                              u16* __restrict__ O,
                                              int HDIM, int KVH, int win) {
    const int bh = blockIdx.z;
    const int b = bh / cH, h = bh % cH;
    const int kh = h / (cH / KVH);
    const int bm = blockIdx.y * 128;   // q tile
    const int bn = blockIdx.x * 128;   // d tile

    __shared__ u16 As[128 * 64];
    __shared__ u16 Bs[128 * 64];
    const int tid = threadIdx.x;
    const int lane = tid & 63;
    const int w = tid >> 6;
    const int wr = (w >> 1) * 64, wc = (w & 1) * 64;
    const int r15 = lane & 15, hi16 = lane >> 4;

    const u16* Ap = P + (size_t)bh * cS * 2048;
    const u16* Bv = Vt + ((size_t)b * KVH + kh) * HDIM * cS;

    f32x4 acc[4][4];
#pragma unroll
    for (int m = 0; m < 4; ++m)
#pragma unroll
        for (int n = 0; n < 4; ++n) acc[m][n] = (f32x4){0.f, 0.f, 0.f, 0.f};

    int rA[4], cA[4], wl[4];
#pragma unroll
    for (int j = 0; j < 4; ++j) {
        const int c = tid + j * 256;
        rA[j] = c >> 3; cA[j] = (c & 7) * 8;
        wl[j] = swzK(rA[j], c & 7);
    }

    const int klo = (win > 0) ? (max(0, bm - win + 1) & ~63) : 0;
    const int khi = min(bm + 128, cS);

    for (int k0 = klo; k0 < khi; k0 += 64) {
        uint4 av[4], bv[4];
#pragma unroll
        for (int j = 0; j < 4; ++j) {
            av[j] = *(const uint4*)&Ap[(size_t)(bm + rA[j]) * 2048 + k0 + cA[j]];
            bv[j] = *(const uint4*)&Bv[(size_t)(bn + rA[j]) * cS + k0 + cA[j]];
        }
        __syncthreads();
#pragma unroll
        for (int j = 0; j < 4; ++j) {
            *(uint4*)&As[wl[j]] = av[j];
            *(uint4*)&Bs[wl[j]] = bv[j];
        }
        __syncthreads();
#pragma unroll
        for (int kk = 0; kk < 2; ++kk) {
            f16x8 af[4], bf4[4];
#pragma unroll
            for (int m = 0; m < 4; ++m)
                af[m] = *(const f16x8*)&As[swzK(wr + m * 16 + r15, kk * 4 + hi16)];
#pragma unroll
            for (int n = 0; n < 4; ++n)
                bf4[n] = *(const f16x8*)&Bs[swzK(wc + n * 16 + r15, kk * 4 + hi16)];
#pragma unroll
            for (int m = 0; m < 4; ++m)
#pragma unroll
                for (int n = 0; n < 4; ++n)
                    acc[m][n] = __builtin_amdgcn_mfma_f32_16x16x32_f16(af[m], bf4[n], acc[m][n], 0, 0, 0);
        }
    }
    const int ldo = cH * HDIM;
#pragma unroll
    for (int m = 0; m < 4; ++m)
#pragma unroll
        for (int n = 0; n < 4; ++n)
#pragma unroll
            for (int r = 0; r < 4; ++r) {
                const int q = bm + wr + m * 16 + hi16 * 4 + r;
                const int d = bn + wc + n * 16 + r15;
                O[(size_t)(b * cS + q) * ldo + h * HDIM + d] = f2h(acc[m][n][r]);
            }
}

// ---------------------------------------------------------------------------
extern "C" void kernel_launch(void* const* d_in, const int* in_sizes, int n_in,
                              void* d_out, int out_size, void* d_ws, size_t ws_size,
                              hipStream_t stream) {
    (void)in_sizes; (void)n_in; (void)out_size; (void)ws_size;
    const int*   tokens = (const int*)  d_in[0];
    const int*   tlen   = (const int*)  d_in[1];
    const float* embed  = (const float*)d_in[2];
    const float* norm_w = (const float*)d_in[3];
    const float* s_wq   = (const float*)d_in[4];
    const float* s_wk   = (const float*)d_in[5];
    const float* s_wv   = (const float*)d_in[6];
    const float* s_wo   = (const float*)d_in[7];
    const float* s_qn   = (const float*)d_in[8];
    const float* s_kn   = (const float*)d_in[9];
    const float* s_wg   = (const float*)d_in[10];
    const float* s_wu   = (const float*)d_in[11];
    const float* s_wd   = (const float*)d_in[12];
    const float* s_ln1  = (const float*)d_in[13];
    const float* s_ln2  = (const float*)d_in[14];
    const float* s_ln3  = (const float*)d_in[15];
    const float* s_ln4  = (const float*)d_in[16];
    const float* s_scal = (const float*)d_in[17];
    const float* g_wq   = (const float*)d_in[18];
    const float* g_wk   = (const float*)d_in[19];
    const float* g_wo   = (const float*)d_in[20];
    const float* g_qn   = (const float*)d_in[21];
    const float* g_kn   = (const float*)d_in[22];
    const float* g_wg   = (const float*)d_in[23];
    const float* g_wu   = (const float*)d_in[24];
    const float* g_wd   = (const float*)d_in[25];
    const float* g_ln1  = (const float*)d_in[26];
    const float* g_ln2  = (const float*)d_in[27];
    const float* g_ln3  = (const float*)d_in[28];
    const float* g_ln4  = (const float*)d_in[29];
    const float* g_scal = (const float*)d_in[30];

    // workspace (peak <156 MiB), phase-disjoint (round-13 plan)
    char* w8 = (char*)d_ws;
    float* x   = (float*)(w8);
    u16*   ab  = (u16*)(w8 + 16 * MB);
    u16*   wp  = (u16*)(w8 + 24 * MB);
    u16*   Qb  = (u16*)(w8 + 24 * MB);
    u16*   Ob  = (u16*)(w8 + 24 * MB);
    u16*   embH= (u16*)(w8 + 24 * MB);
    u16*   t0b = (u16*)(w8 + 56 * MB);
    u16*   Kb  = (u16*)(w8 + 58 * MB);
    u16*   Vt  = (u16*)(w8 + 75 * MB);
    float* qkg = (float*)(w8 + 84 * MB);
    float* scores = (float*)(w8 + 84 * MB);
    u16*   Pb  = (u16*)(w8 + 84 * MB);
    u16*   wo2 = (u16*)(w8 + 84 * MB);
    u16*   t1b = (u16*)(w8 + 88 * MB);
    float* r0  = (float*)(w8 + 116 * MB);
    float* fo  = (float*)(w8 + 120 * MB);
    float* vf  = (float*)(w8 + 132 * MB);

    auto tcast = [&](const float* in, u16* outp, int K, int N, int ldin) {
        tcast_kernel<<<dim3(N / 32, K / 32), 256, 0, stream>>>(in, outp, K, N, ldin);
    };
    auto gemmF = [&](const u16* A, const u16* Bt, float* C, int N, int K, int ldc) {
        gemm_f16<false, false><<<16 * (N / 128), 256, 0, stream>>>(A, Bt, C, nullptr, 16, K, ldc);
    };
    auto g256H = [&](const u16* A, const u16* Bt, u16* C, int N, int K, int ldc) {
        gemm256<true, false><<<8 * (N / 256), 512, 0, stream>>>(A, Bt, C, nullptr, 8, K, ldc);
    };
    auto g256HG = [&](const u16* A, const u16* Bt, u16* C, const u16* gate,
                      int N, int K, int ldc) {
        gemm256<true, true><<<8 * (N / 256), 512, 0, stream>>>(A, Bt, C, gate, 8, K, ldc);
    };

    // attention core: Qb/Kb fp16 + vf fp32 (dense) ready; writes Ob fp16
    auto attention = [&](int HDIM, int KVH, int win) {
        vtrans_kernel<<<dim3(HDIM / 32, cS / 32, cB * KVH), 256, 0, stream>>>(vf, Vt, HDIM, KVH);
        qk_f16<<<dim3(cS / 128, cS / 128, cB * cH), 256, 0, stream>>>(
            Qb, Kb, scores, HDIM, KVH, win);
        softmax_kernel<<<dim3(cS, cB * cH), 256, 0, stream>>>(scores, tlen, win);
        pv_f16<<<dim3(HDIM / 128, cS / 128, cB * cH), 256, 0, stream>>>(
            Pb, Vt, Ob, HDIM, KVH, win);
    };

    embed_kernel<<<cM, 256, 0, stream>>>(tokens, embed, x);

    // ================= block 1: sliding-window =================
    rms_f16_kernel<<<cM, 256, 0, stream>>>(x, s_ln1, ab, cD);
    tcast(s_wq, wp, cD, cH * cHD, cH * cHD);
    tcast(s_wk, wp + (size_t)2048 * cD, cD, cKV * cHD, cKV * cHD);
    tcast(s_wv, wp + (size_t)3072 * cD, cD, cKV * cHD, cKV * cHD);
    gemmF(ab, wp, qkg, 4096, cD, 4096);                               // [M,4096] q|k|v
    rms_kernel<<<cM * cKV, 256, 0, stream>>>(qkg + 3072, nullptr, vf, cHD, 4096, cKV);
    rmsrope_kernel<<<cM * cH, 128, 0, stream>>>(qkg, s_qn, Qb, cH, cHD, cHD, 10000.f, 4096);
    rmsrope_kernel<<<cM * cKV, 128, 0, stream>>>(qkg + 2048, s_kn, Kb, cKV, cHD, cHD, 10000.f, 4096);
    attention(cHD, cKV, cWIN);
    tcast(s_wo, wo2, cH * cHD, cD, cD);
    gemmF(Ob, wo2, r0, cD, cH * cHD, cD);
    addnorm_kernel<<<cM, 256, 0, stream>>>(x, r0, s_ln2, nullptr, s_ln3, x, ab);
    tcast(s_wg, wp, cD, cF, cF);
    g256H(ab, wp, t1b, cF, cD, cF);                 // gate -> t1b
    tcast(s_wu, wp, cD, cF, cF);
    g256HG(ab, wp, t0b, t1b, cF, cD, cF);           // gelu(gate)*up -> t0b
    tcast(s_wd, wp, cF, cD, cD);
    gemmF(t0b, wp, fo, cD, cF, cD);
    addnorm_kernel<<<cM, 256, 0, stream>>>(x, fo, s_ln4, s_scal, g_ln1, x, ab);

    // ================= block 2: global =================
    tcast(g_wq, wp, cD, cH * cGHD, cH * cGHD);
    tcast(g_wk, wp + (size_t)4096 * cD, cD, cGKV * cGHD, cGKV * cGHD);
    gemmF(ab, wp, qkg, 6144, cD, 6144);                               // [M,6144] q|k
    rms_kernel<<<cM * cGKV, 256, 0, stream>>>(qkg + 4096, nullptr, vf, cGHD, 6144, cGKV);
    rmsrope_kernel<<<cM * cH, 128, 0, stream>>>(qkg, g_qn, Qb, cH, cGHD, cROT, 1000000.f, 6144);
    rmsrope_kernel<<<cM * cGKV, 128, 0, stream>>>(qkg + 4096, g_kn, Kb, cGKV, cGHD, cROT, 1000000.f, 6144);
    attention(cGHD, cGKV, 0);
    tcast(g_wo, wo2, cH * cGHD, cD, cD);
    gemmF(Ob, wo2, r0, cD, cH * cGHD, cD);
    addnorm_kernel<<<cM, 256, 0, stream>>>(x, r0, g_ln2, nullptr, g_ln3, x, ab);
    tcast(g_wg, wp, cD, cF, cF);
    g256H(ab, wp, t1b, cF, cD, cF);
    tcast(g_wu, wp, cD, cF, cF);
    g256HG(ab, wp, t0b, t1b, cF, cD, cF);
    tcast(g_wd, wp, cF, cD, cD);
    gemmF(t0b, wp, fo, cD, cF, cD);
    addnorm_kernel<<<cM, 256, 0, stream>>>(x, fo, g_ln4, g_scal, norm_w, x, ab);

    // ================= logits: cast embed to fp16, 256^2 GEMM ==========
    cast_f16_kernel<<<(cV * cD / 4 + 255) / 256, 256, 0, stream>>>(embed, embH, cV * cD);
    gemm256<false, false><<<8 * (cV / 256), 512, 0, stream>>>(
        ab, embH, (float*)d_out, nullptr, 8, cD, cV);
}